// Round 1
// baseline (14377.773 us; speedup 1.0000x reference)
//
#include <hip/hip_runtime.h>
#include <math.h>

constexpr int SEQ    = 2048;
constexpr int DMODEL = 768;
constexpr int NHEAD  = 12;
constexpr int DHEAD  = 64;
constexpr int NV     = 50257;
constexpr int NLAYER = 4;

// ---------------- embedding: x[t] = wte[idx[t]] + wpe[t] ----------------
__global__ void embed_kernel(const int* __restrict__ idx, const float* __restrict__ wte,
                             const float* __restrict__ wpe, float* __restrict__ x) {
    int t = blockIdx.x;
    int tok = idx[t];
    for (int d = threadIdx.x; d < DMODEL; d += blockDim.x)
        x[t * DMODEL + d] = wte[(size_t)tok * DMODEL + d] + wpe[t * DMODEL + d];
}

// ---------------- layernorm: one block per row (768 cols) ----------------
__global__ __launch_bounds__(256) void ln_kernel(const float* __restrict__ x,
                                                 const float* __restrict__ w,
                                                 const float* __restrict__ b,
                                                 float* __restrict__ out) {
    __shared__ float red[8];
    int row = blockIdx.x, tid = threadIdx.x;
    const float* xr = x + (size_t)row * DMODEL;
    float v[3];
    float s = 0.f, ss = 0.f;
#pragma unroll
    for (int j = 0; j < 3; j++) {
        v[j] = xr[tid + j * 256];
        s += v[j];
        ss += v[j] * v[j];
    }
#pragma unroll
    for (int off = 32; off; off >>= 1) {
        s  += __shfl_down(s,  off, 64);
        ss += __shfl_down(ss, off, 64);
    }
    int wid = tid >> 6, lane = tid & 63;
    if (lane == 0) { red[wid] = s; red[4 + wid] = ss; }
    __syncthreads();
    s  = red[0] + red[1] + red[2] + red[3];
    ss = red[4] + red[5] + red[6] + red[7];
    float mean = s * (1.0f / DMODEL);
    float var  = ss * (1.0f / DMODEL) - mean * mean;
    float rstd = rsqrtf(var + 1e-5f);
#pragma unroll
    for (int j = 0; j < 3; j++) {
        int d = tid + j * 256;
        out[(size_t)row * DMODEL + d] = (v[j] - mean) * rstd * w[d] + b[d];
    }
}

// ---------------- generic GEMM: C[M,N] = act(A[M,K] @ W[K,N] + bias + R) ----------------
// 64x64 tile, BK=16, 256 threads, 4x4 per thread. M is multiple of 64; N guarded.
template <int ACT, int RES>
__global__ __launch_bounds__(256) void gemm_kernel(const float* __restrict__ A,
                                                   const float* __restrict__ W,
                                                   const float* __restrict__ bias,
                                                   const float* __restrict__ R,
                                                   float* __restrict__ C,
                                                   int N, int K) {
    __shared__ float As[64][17];
    __shared__ float Ws[16][64];
    int tid = threadIdx.x;
    int bm = blockIdx.y << 6, bn = blockIdx.x << 6;
    int tr = (tid >> 4) << 2, tc = (tid & 15) << 2;
    float acc[4][4] = {};
    for (int k0 = 0; k0 < K; k0 += 16) {
#pragma unroll
        for (int i = 0; i < 4; i++) {
            int id = tid + (i << 8);
            int r = id >> 4, c = id & 15;
            As[r][c] = A[(size_t)(bm + r) * K + k0 + c];
        }
#pragma unroll
        for (int i = 0; i < 4; i++) {
            int id = tid + (i << 8);
            int r = id >> 6, c = id & 63;
            int col = bn + c;
            Ws[r][c] = (col < N) ? W[(size_t)(k0 + r) * N + col] : 0.0f;
        }
        __syncthreads();
#pragma unroll
        for (int kk = 0; kk < 16; kk++) {
            float a[4], bv[4];
#pragma unroll
            for (int i = 0; i < 4; i++) a[i] = As[tr + i][kk];
#pragma unroll
            for (int j = 0; j < 4; j++) bv[j] = Ws[kk][tc + j];
#pragma unroll
            for (int i = 0; i < 4; i++)
#pragma unroll
                for (int j = 0; j < 4; j++) acc[i][j] += a[i] * bv[j];
        }
        __syncthreads();
    }
#pragma unroll
    for (int i = 0; i < 4; i++) {
        int row = bm + tr + i;
#pragma unroll
        for (int j = 0; j < 4; j++) {
            int col = bn + tc + j;
            if (col < N) {
                float v = acc[i][j] + bias[col];
                if (RES) v += R[(size_t)row * N + col];
                if (ACT == 1) {
                    float u = v;
                    v = 0.5f * u * (1.0f + tanhf(0.7978845608028654f * (u + 0.044715f * u * u * u)));
                }
                C[(size_t)row * N + col] = v;
            }
        }
    }
}

// ---------------- attention: one block per (query row, head) ----------------
// qkv layout: [t][3*DMODEL], q at h*64, k at 768+h*64, v at 1536+h*64
__global__ __launch_bounds__(256) void attn_kernel(const float* __restrict__ qkv,
                                                   float* __restrict__ o) {
    __shared__ float s[SEQ];
    __shared__ float qv[DHEAD];
    __shared__ float red[8];
    __shared__ float ored[4][DHEAD];
    int q = blockIdx.x, h = blockIdx.y, tid = threadIdx.x;
    int nk = q + 1;
    if (tid < DHEAD) qv[tid] = qkv[(size_t)q * 2304 + h * DHEAD + tid];
    __syncthreads();
    // phase 1: scores
    const float4* q4 = (const float4*)qv;
    for (int k = tid; k < nk; k += 256) {
        const float4* kr = (const float4*)(qkv + (size_t)k * 2304 + 768 + h * DHEAD);
        float acc = 0.f;
#pragma unroll
        for (int d = 0; d < 16; d++) {
            float4 a = q4[d], b = kr[d];
            acc += a.x * b.x + a.y * b.y + a.z * b.z + a.w * b.w;
        }
        s[k] = acc * 0.125f;
    }
    __syncthreads();
    // phase 2: max
    float m = -1e30f;
    for (int k = tid; k < nk; k += 256) m = fmaxf(m, s[k]);
#pragma unroll
    for (int off = 32; off; off >>= 1) m = fmaxf(m, __shfl_down(m, off, 64));
    int wid = tid >> 6, lane = tid & 63;
    if (lane == 0) red[wid] = m;
    __syncthreads();
    m = fmaxf(fmaxf(red[0], red[1]), fmaxf(red[2], red[3]));
    // exp + sum
    float sum = 0.f;
    for (int k = tid; k < nk; k += 256) {
        float p = expf(s[k] - m);
        s[k] = p;
        sum += p;
    }
    __syncthreads();
#pragma unroll
    for (int off = 32; off; off >>= 1) sum += __shfl_down(sum, off, 64);
    if (lane == 0) red[4 + wid] = sum;
    __syncthreads();
    sum = red[4] + red[5] + red[6] + red[7];
    float inv = 1.0f / sum;
    // phase 3: o = P @ V
    int d = tid & 63, part = tid >> 6;
    float acc = 0.f;
    for (int k = part; k < nk; k += 4)
        acc += s[k] * qkv[(size_t)k * 2304 + 1536 + h * DHEAD + d];
    ored[part][d] = acc;
    __syncthreads();
    if (part == 0) {
        float v = (ored[0][d] + ored[1][d] + ored[2][d] + ored[3][d]) * inv;
        o[(size_t)q * DMODEL + h * DHEAD + d] = v;
    }
}

// ---------------- logsumexp per row over vocab ----------------
__global__ __launch_bounds__(256) void lse_kernel(const float* __restrict__ logits,
                                                  float* __restrict__ lse) {
    __shared__ float redm[4], reds[4];
    int row = blockIdx.x, tid = threadIdx.x;
    const float* lr = logits + (size_t)row * NV;
    float m = -1e30f, sum = 0.f;
    for (int c = tid; c < NV; c += 256) {
        float v = lr[c];
        if (v > m) { sum = sum * expf(m - v) + 1.0f; m = v; }
        else       { sum += expf(v - m); }
    }
#pragma unroll
    for (int off = 32; off; off >>= 1) {
        float m2 = __shfl_down(m, off, 64), s2 = __shfl_down(sum, off, 64);
        float M = fmaxf(m, m2);
        sum = sum * expf(m - M) + s2 * expf(m2 - M);
        m = M;
    }
    int wid = tid >> 6, lane = tid & 63;
    if (lane == 0) { redm[wid] = m; reds[wid] = sum; }
    __syncthreads();
    if (tid == 0) {
        float M = fmaxf(fmaxf(redm[0], redm[1]), fmaxf(redm[2], redm[3]));
        float S = reds[0] * expf(redm[0] - M) + reds[1] * expf(redm[1] - M) +
                  reds[2] * expf(redm[2] - M) + reds[3] * expf(redm[3] - M);
        lse[row] = M + logf(S);
    }
}

// ---------------- loss = mean_t (lse[t] - logit[t, target[t]]) ----------------
__global__ __launch_bounds__(256) void loss_kernel(const float* __restrict__ logits,
                                                   const float* __restrict__ lse,
                                                   const int* __restrict__ targets,
                                                   float* __restrict__ out) {
    __shared__ float red[4];
    int tid = threadIdx.x;
    float acc = 0.f;
    for (int t = tid; t < SEQ; t += 256)
        acc += lse[t] - logits[(size_t)t * NV + targets[t]];
#pragma unroll
    for (int off = 32; off; off >>= 1) acc += __shfl_down(acc, off, 64);
    int wid = tid >> 6, lane = tid & 63;
    if (lane == 0) red[wid] = acc;
    __syncthreads();
    if (tid == 0) out[0] = (red[0] + red[1] + red[2] + red[3]) * (1.0f / SEQ);
}

extern "C" void kernel_launch(void* const* d_in, const int* in_sizes, int n_in,
                              void* d_out, int out_size, void* d_ws, size_t ws_size,
                              hipStream_t stream) {
    const int*   idx         = (const int*)d_in[0];
    const int*   targets     = (const int*)d_in[1];
    const float* wte         = (const float*)d_in[2];
    const float* wpe         = (const float*)d_in[3];
    const float* ln1_w       = (const float*)d_in[4];
    const float* ln1_b       = (const float*)d_in[5];
    const float* attn_w      = (const float*)d_in[6];
    const float* attn_b      = (const float*)d_in[7];
    const float* attn_proj_w = (const float*)d_in[8];
    const float* attn_proj_b = (const float*)d_in[9];
    const float* ln2_w       = (const float*)d_in[10];
    const float* ln2_b       = (const float*)d_in[11];
    const float* fc_w        = (const float*)d_in[12];
    const float* fc_b        = (const float*)d_in[13];
    const float* mlp_proj_w  = (const float*)d_in[14];
    const float* mlp_proj_b  = (const float*)d_in[15];
    const float* lnf_w       = (const float*)d_in[16];
    const float* lnf_b       = (const float*)d_in[17];
    const float* head_w      = (const float*)d_in[18];
    const float* head_b      = (const float*)d_in[19];

    float* logits = (float*)d_out;
    float* loss   = logits + (size_t)SEQ * NV;

    float* x   = (float*)d_ws;          // [SEQ, DMODEL]
    float* h   = x + SEQ * DMODEL;      // [SEQ, DMODEL]
    float* o   = h + SEQ * DMODEL;      // [SEQ, DMODEL]
    float* lse = o + SEQ * DMODEL;      // [SEQ]
    float* big = lse + SEQ;             // [SEQ, 3072] (also holds qkv [SEQ,2304])

    embed_kernel<<<SEQ, 256, 0, stream>>>(idx, wte, wpe, x);

    for (int l = 0; l < NLAYER; l++) {
        ln_kernel<<<SEQ, 256, 0, stream>>>(x, ln1_w + l * DMODEL, ln1_b + l * DMODEL, h);
        gemm_kernel<0, 0><<<dim3(2304 / 64, SEQ / 64), 256, 0, stream>>>(
            h, attn_w + (size_t)l * DMODEL * 2304, attn_b + l * 2304, nullptr, big, 2304, DMODEL);
        attn_kernel<<<dim3(SEQ, NHEAD), 256, 0, stream>>>(big, o);
        gemm_kernel<0, 1><<<dim3(DMODEL / 64, SEQ / 64), 256, 0, stream>>>(
            o, attn_proj_w + (size_t)l * DMODEL * DMODEL, attn_proj_b + l * DMODEL, x, x, DMODEL, DMODEL);
        ln_kernel<<<SEQ, 256, 0, stream>>>(x, ln2_w + l * DMODEL, ln2_b + l * DMODEL, h);
        gemm_kernel<1, 0><<<dim3(3072 / 64, SEQ / 64), 256, 0, stream>>>(
            h, fc_w + (size_t)l * DMODEL * 3072, fc_b + l * 3072, nullptr, big, 3072, DMODEL);
        gemm_kernel<0, 1><<<dim3(DMODEL / 64, SEQ / 64), 256, 0, stream>>>(
            big, mlp_proj_w + (size_t)l * 3072 * DMODEL, mlp_proj_b + l * DMODEL, x, x, DMODEL, 3072);
    }

    ln_kernel<<<SEQ, 256, 0, stream>>>(x, lnf_w, lnf_b, h);
    gemm_kernel<0, 0><<<dim3((NV + 63) / 64, SEQ / 64), 256, 0, stream>>>(
        h, head_w, head_b, nullptr, logits, NV, DMODEL);
    lse_kernel<<<SEQ, 256, 0, stream>>>(logits, lse);
    loss_kernel<<<1, 256, 0, stream>>>(logits, lse, targets, loss);
}

// Round 2
// 3157.542 us; speedup vs baseline: 4.5535x; 4.5535x over previous
//
#include <hip/hip_runtime.h>
#include <hip/hip_bf16.h>
#include <math.h>

using bf16   = __hip_bfloat16;
using f32x4  = __attribute__((ext_vector_type(4))) float;
using bf16x8 = __attribute__((ext_vector_type(8))) short;

constexpr int SEQ    = 2048;
constexpr int DMODEL = 768;
constexpr int NHEAD  = 12;
constexpr int NV     = 50257;
constexpr int NVPAD  = 50304;   // padded to multiple of 128
constexpr int NLAYER = 4;

__device__ __forceinline__ void gload_lds16(const void* g, void* s) {
    __builtin_amdgcn_global_load_lds((const __attribute__((address_space(1))) void*)g,
                                     (__attribute__((address_space(3))) void*)s, 16, 0, 0);
}

// ---------------- embedding: x[t] = wte[idx[t]] + wpe[t] (fp32) ----------------
__global__ __launch_bounds__(192) void embed_kernel(const int* __restrict__ idx,
                                                    const float* __restrict__ wte,
                                                    const float* __restrict__ wpe,
                                                    float* __restrict__ x) {
    int t = blockIdx.x;
    int tok = idx[t];
    const float4* a = (const float4*)(wte + (size_t)tok * DMODEL);
    const float4* b = (const float4*)(wpe + (size_t)t * DMODEL);
    float4* o = (float4*)(x + (size_t)t * DMODEL);
    int d = threadIdx.x;
    float4 u = a[d], v = b[d];
    u.x += v.x; u.y += v.y; u.z += v.z; u.w += v.w;
    o[d] = u;
}

// ---------------- layernorm: fp32 in, bf16 out ----------------
__global__ __launch_bounds__(256) void ln_kernel(const float* __restrict__ x,
                                                 const float* __restrict__ w,
                                                 const float* __restrict__ b,
                                                 bf16* __restrict__ out) {
    __shared__ float red[8];
    int row = blockIdx.x, tid = threadIdx.x;
    const float* xr = x + (size_t)row * DMODEL;
    float v[3];
    float s = 0.f, ss = 0.f;
#pragma unroll
    for (int j = 0; j < 3; j++) {
        v[j] = xr[tid + j * 256];
        s += v[j];
        ss += v[j] * v[j];
    }
#pragma unroll
    for (int off = 32; off; off >>= 1) {
        s  += __shfl_down(s,  off, 64);
        ss += __shfl_down(ss, off, 64);
    }
    int wid = tid >> 6, lane = tid & 63;
    if (lane == 0) { red[wid] = s; red[4 + wid] = ss; }
    __syncthreads();
    s  = red[0] + red[1] + red[2] + red[3];
    ss = red[4] + red[5] + red[6] + red[7];
    float mean = s * (1.0f / DMODEL);
    float var  = ss * (1.0f / DMODEL) - mean * mean;
    float rstd = rsqrtf(var + 1e-5f);
#pragma unroll
    for (int j = 0; j < 3; j++) {
        int d = tid + j * 256;
        out[(size_t)row * DMODEL + d] = __float2bfloat16((v[j] - mean) * rstd * w[d] + b[d]);
    }
}

// ---------------- transpose + fp32->bf16: W[K][N] -> Wt[Npad][K] ----------------
__global__ __launch_bounds__(256) void transp_kernel(const float* __restrict__ W,
                                                     bf16* __restrict__ Wt,
                                                     int K, int N) {
    __shared__ float t[64][65];
    int n0 = blockIdx.x << 6, k0 = blockIdx.y << 6;
    int tid = threadIdx.x;
#pragma unroll
    for (int i = 0; i < 16; i++) {
        int id = tid + (i << 8);
        int r = id >> 6, c = id & 63;
        int n = n0 + c;
        t[r][c] = (n < N) ? W[(size_t)(k0 + r) * N + n] : 0.0f;
    }
    __syncthreads();
#pragma unroll
    for (int i = 0; i < 16; i++) {
        int id = tid + (i << 8);
        int nr = id >> 6, kc = id & 63;
        Wt[(size_t)(n0 + nr) * K + k0 + kc] = __float2bfloat16(t[kc][nr]);
    }
}

// ---------------- MFMA GEMM: C[M,N] = epi(A[M,K]bf16 @ Wt[N,K]bf16^T) ----------------
// 128x128 tile, BK=32, 256 threads = 4 waves (2x2 of 64x64).
// LDS linear [128][32]bf16, content XOR-swizzled at 16B slots: slot ^= (row>>1)&3.
template <int ACT, int RES, int OBF>
__global__ __launch_bounds__(256) void mgemm_kernel(const short* __restrict__ A,
                                                    const short* __restrict__ Wt,
                                                    const float* __restrict__ bias,
                                                    const float* __restrict__ res,
                                                    float* __restrict__ outf,
                                                    bf16* __restrict__ outb,
                                                    int N, int K) {
    __shared__ short As[4096];   // 8 KB
    __shared__ short Bs[4096];
    int tid = threadIdx.x, lane = tid & 63, wid = tid >> 6;
    int bm = blockIdx.y << 7, bn = blockIdx.x << 7;
    int wr = (wid >> 1) << 6, wc = (wid & 1) << 6;
    f32x4 acc[4][4] = {};
    int rA = tid >> 2, sA = tid & 3;
    int q = lane >> 4, rr = lane & 15;

    for (int k0 = 0; k0 < K; k0 += 32) {
#pragma unroll
        for (int i = 0; i < 2; i++) {
            int r = rA + (i << 6);
            int gc = k0 + ((sA ^ ((r >> 1) & 3)) << 3);
            char* dstA = (char*)As + (i << 12) + (wid << 10);
            char* dstB = (char*)Bs + (i << 12) + (wid << 10);
            gload_lds16(A  + (size_t)(bm + r) * K + gc, dstA);
            gload_lds16(Wt + (size_t)(bn + r) * K + gc, dstB);
        }
        __syncthreads();
        bf16x8 af[4], bfr[4];
#pragma unroll
        for (int m = 0; m < 4; m++) {
            int rowa = wr + (m << 4) + rr;
            af[m]  = *(const bf16x8*)((const char*)As + rowa * 64 + ((q ^ ((rowa >> 1) & 3)) << 4));
            int rowb = wc + (m << 4) + rr;
            bfr[m] = *(const bf16x8*)((const char*)Bs + rowb * 64 + ((q ^ ((rowb >> 1) & 3)) << 4));
        }
#pragma unroll
        for (int m = 0; m < 4; m++)
#pragma unroll
            for (int n = 0; n < 4; n++)
                acc[m][n] = __builtin_amdgcn_mfma_f32_16x16x32_bf16(af[m], bfr[n], acc[m][n], 0, 0, 0);
        __syncthreads();
    }

    int cl = lane & 15, rg = (lane >> 4) << 2;
#pragma unroll
    for (int n = 0; n < 4; n++) {
        int col = bn + wc + (n << 4) + cl;
        if (col < N) {
            float bcol = bias[col];
#pragma unroll
            for (int m = 0; m < 4; m++) {
#pragma unroll
                for (int i = 0; i < 4; i++) {
                    int row = bm + wr + (m << 4) + rg + i;
                    float v = acc[m][n][i] + bcol;
                    if (RES) v += res[(size_t)row * N + col];
                    if (ACT) v = v / (1.0f + __expf(-1.5957691216057308f * (v + 0.044715f * v * v * v)));
                    if (OBF) outb[(size_t)row * N + col] = __float2bfloat16(v);
                    else     outf[(size_t)row * N + col] = v;
                }
            }
        }
    }
}

// ---------------- flash attention: block = (64-row Q-tile, head), fp32 ----------------
__global__ __launch_bounds__(256) void attn_kernel(const float* __restrict__ qkv,
                                                   bf16* __restrict__ o) {
    __shared__ float Qs[64][68], Ks[64][68], Vs[64][68], Ps[64][68];
    int qt = gridDim.x - 1 - blockIdx.x;   // big tiles first
    int h = blockIdx.y, tid = threadIdx.x;
    int q0 = qt << 6;
#pragma unroll
    for (int i = 0; i < 4; i++) {
        int id = tid + (i << 8);
        int r = id >> 4, c4 = (id & 15) << 2;
        float4 v = *(const float4*)(qkv + (size_t)(q0 + r) * 2304 + h * 64 + c4);
        v.x *= 0.125f; v.y *= 0.125f; v.z *= 0.125f; v.w *= 0.125f;
        *(float4*)&Qs[r][c4] = v;
    }
    int tr = (tid >> 4) << 2, tc = (tid & 15) << 2;
    float m_i[4] = {-1e30f, -1e30f, -1e30f, -1e30f};
    float l_i[4] = {};
    float oa[4][4] = {};

    for (int kt = 0; kt <= qt; kt++) {
        __syncthreads();
#pragma unroll
        for (int i = 0; i < 4; i++) {
            int id = tid + (i << 8);
            int r = id >> 4, c4 = (id & 15) << 2;
            const float* base = qkv + (size_t)((kt << 6) + r) * 2304 + h * 64 + c4;
            *(float4*)&Ks[r][c4] = *(const float4*)(base + 768);
            *(float4*)&Vs[r][c4] = *(const float4*)(base + 1536);
        }
        __syncthreads();
        float s[4][4] = {};
#pragma unroll
        for (int d0 = 0; d0 < 64; d0 += 4) {
            float4 qv[4], kv[4];
#pragma unroll
            for (int i = 0; i < 4; i++) qv[i] = *(const float4*)&Qs[tr + i][d0];
#pragma unroll
            for (int j = 0; j < 4; j++) kv[j] = *(const float4*)&Ks[tc + j][d0];
#pragma unroll
            for (int i = 0; i < 4; i++)
#pragma unroll
                for (int j = 0; j < 4; j++)
                    s[i][j] += qv[i].x * kv[j].x + qv[i].y * kv[j].y +
                               qv[i].z * kv[j].z + qv[i].w * kv[j].w;
        }
        if (kt == qt) {
#pragma unroll
            for (int i = 0; i < 4; i++)
#pragma unroll
                for (int j = 0; j < 4; j++)
                    if (tc + j > tr + i) s[i][j] = -1e30f;
        }
#pragma unroll
        for (int i = 0; i < 4; i++) {
            float rm = fmaxf(fmaxf(s[i][0], s[i][1]), fmaxf(s[i][2], s[i][3]));
            rm = fmaxf(rm, __shfl_xor(rm, 1, 16));
            rm = fmaxf(rm, __shfl_xor(rm, 2, 16));
            rm = fmaxf(rm, __shfl_xor(rm, 4, 16));
            rm = fmaxf(rm, __shfl_xor(rm, 8, 16));
            float mn = fmaxf(m_i[i], rm);
            float sc = __expf(m_i[i] - mn);
            float rs = 0.f;
#pragma unroll
            for (int j = 0; j < 4; j++) { s[i][j] = __expf(s[i][j] - mn); rs += s[i][j]; }
            rs += __shfl_xor(rs, 1, 16); rs += __shfl_xor(rs, 2, 16);
            rs += __shfl_xor(rs, 4, 16); rs += __shfl_xor(rs, 8, 16);
            l_i[i] = l_i[i] * sc + rs;
            m_i[i] = mn;
#pragma unroll
            for (int j = 0; j < 4; j++) { oa[i][j] *= sc; Ps[tr + i][tc + j] = s[i][j]; }
        }
        __syncthreads();
#pragma unroll
        for (int k0 = 0; k0 < 64; k0 += 4) {
            float4 pv[4], vv[4];
#pragma unroll
            for (int i = 0; i < 4; i++) pv[i] = *(const float4*)&Ps[tr + i][k0];
#pragma unroll
            for (int k = 0; k < 4; k++) vv[k] = *(const float4*)&Vs[k0 + k][tc];
#pragma unroll
            for (int i = 0; i < 4; i++) {
                oa[i][0] += pv[i].x * vv[0].x + pv[i].y * vv[1].x + pv[i].z * vv[2].x + pv[i].w * vv[3].x;
                oa[i][1] += pv[i].x * vv[0].y + pv[i].y * vv[1].y + pv[i].z * vv[2].y + pv[i].w * vv[3].y;
                oa[i][2] += pv[i].x * vv[0].z + pv[i].y * vv[1].z + pv[i].z * vv[2].z + pv[i].w * vv[3].z;
                oa[i][3] += pv[i].x * vv[0].w + pv[i].y * vv[1].w + pv[i].z * vv[2].w + pv[i].w * vv[3].w;
            }
        }
    }
#pragma unroll
    for (int i = 0; i < 4; i++) {
        float inv = 1.0f / l_i[i];
#pragma unroll
        for (int j = 0; j < 4; j++)
            o[(size_t)(q0 + tr + i) * DMODEL + h * 64 + tc + j] = __float2bfloat16(oa[i][j] * inv);
    }
}

// ---------------- logsumexp per row over vocab ----------------
__global__ __launch_bounds__(256) void lse_kernel(const float* __restrict__ logits,
                                                  float* __restrict__ lse) {
    __shared__ float redm[4], reds[4];
    int row = blockIdx.x, tid = threadIdx.x;
    const float* lr = logits + (size_t)row * NV;
    float m = -1e30f, sum = 0.f;
    for (int c = tid; c < NV; c += 256) {
        float v = lr[c];
        if (v > m) { sum = sum * __expf(m - v) + 1.0f; m = v; }
        else       { sum += __expf(v - m); }
    }
#pragma unroll
    for (int off = 32; off; off >>= 1) {
        float m2 = __shfl_down(m, off, 64), s2 = __shfl_down(sum, off, 64);
        float M = fmaxf(m, m2);
        sum = sum * __expf(m - M) + s2 * __expf(m2 - M);
        m = M;
    }
    int wid = tid >> 6, lane = tid & 63;
    if (lane == 0) { redm[wid] = m; reds[wid] = sum; }
    __syncthreads();
    if (tid == 0) {
        float M = fmaxf(fmaxf(redm[0], redm[1]), fmaxf(redm[2], redm[3]));
        float S = reds[0] * __expf(redm[0] - M) + reds[1] * __expf(redm[1] - M) +
                  reds[2] * __expf(redm[2] - M) + reds[3] * __expf(redm[3] - M);
        lse[row] = M + logf(S);
    }
}

__global__ __launch_bounds__(256) void loss_kernel(const float* __restrict__ logits,
                                                   const float* __restrict__ lse,
                                                   const int* __restrict__ targets,
                                                   float* __restrict__ out) {
    __shared__ float red[4];
    int tid = threadIdx.x;
    float acc = 0.f;
    for (int t = tid; t < SEQ; t += 256)
        acc += lse[t] - logits[(size_t)t * NV + targets[t]];
#pragma unroll
    for (int off = 32; off; off >>= 1) acc += __shfl_down(acc, off, 64);
    int wid = tid >> 6, lane = tid & 63;
    if (lane == 0) red[wid] = acc;
    __syncthreads();
    if (tid == 0) out[0] = (red[0] + red[1] + red[2] + red[3]) * (1.0f / SEQ);
}

extern "C" void kernel_launch(void* const* d_in, const int* in_sizes, int n_in,
                              void* d_out, int out_size, void* d_ws, size_t ws_size,
                              hipStream_t stream) {
    const int*   idx         = (const int*)d_in[0];
    const int*   targets     = (const int*)d_in[1];
    const float* wte         = (const float*)d_in[2];
    const float* wpe         = (const float*)d_in[3];
    const float* ln1_w       = (const float*)d_in[4];
    const float* ln1_b       = (const float*)d_in[5];
    const float* attn_w      = (const float*)d_in[6];
    const float* attn_b      = (const float*)d_in[7];
    const float* attn_proj_w = (const float*)d_in[8];
    const float* attn_proj_b = (const float*)d_in[9];
    const float* ln2_w       = (const float*)d_in[10];
    const float* ln2_b       = (const float*)d_in[11];
    const float* fc_w        = (const float*)d_in[12];
    const float* fc_b        = (const float*)d_in[13];
    const float* mlp_proj_w  = (const float*)d_in[14];
    const float* mlp_proj_b  = (const float*)d_in[15];
    const float* lnf_w       = (const float*)d_in[16];
    const float* lnf_b       = (const float*)d_in[17];
    const float* head_w      = (const float*)d_in[18];
    const float* head_b      = (const float*)d_in[19];

    float* logits = (float*)d_out;
    float* loss   = logits + (size_t)SEQ * NV;

    char* p = (char*)d_ws;
    float* x    = (float*)p;  p += (size_t)SEQ * DMODEL * 4;
    bf16*  h    = (bf16*)p;   p += (size_t)SEQ * DMODEL * 2;
    bf16*  o    = (bf16*)p;   p += (size_t)SEQ * DMODEL * 2;
    float* qkvb = (float*)p;  p += (size_t)SEQ * 2304 * 4;
    bf16*  fcb  = (bf16*)p;   p += (size_t)SEQ * 3072 * 2;
    float* lse  = (float*)p;  p += (size_t)SEQ * 4;
    bf16*  Wt   = (bf16*)p;   // up to NVPAD*768 bf16 = 77.3 MB, reused per GEMM

    embed_kernel<<<SEQ, 192, 0, stream>>>(idx, wte, wpe, x);

    for (int l = 0; l < NLAYER; l++) {
        ln_kernel<<<SEQ, 256, 0, stream>>>(x, ln1_w + l * DMODEL, ln1_b + l * DMODEL, h);
        transp_kernel<<<dim3(2304 / 64, DMODEL / 64), 256, 0, stream>>>(
            attn_w + (size_t)l * DMODEL * 2304, Wt, DMODEL, 2304);
        mgemm_kernel<0, 0, 0><<<dim3(2304 / 128, SEQ / 128), 256, 0, stream>>>(
            (const short*)h, (const short*)Wt, attn_b + l * 2304, nullptr, qkvb, nullptr, 2304, DMODEL);
        attn_kernel<<<dim3(SEQ / 64, NHEAD), 256, 0, stream>>>(qkvb, o);
        transp_kernel<<<dim3(DMODEL / 64, DMODEL / 64), 256, 0, stream>>>(
            attn_proj_w + (size_t)l * DMODEL * DMODEL, Wt, DMODEL, DMODEL);
        mgemm_kernel<0, 1, 0><<<dim3(DMODEL / 128, SEQ / 128), 256, 0, stream>>>(
            (const short*)o, (const short*)Wt, attn_proj_b + l * DMODEL, x, x, nullptr, DMODEL, DMODEL);
        ln_kernel<<<SEQ, 256, 0, stream>>>(x, ln2_w + l * DMODEL, ln2_b + l * DMODEL, h);
        transp_kernel<<<dim3(3072 / 64, DMODEL / 64), 256, 0, stream>>>(
            fc_w + (size_t)l * DMODEL * 3072, Wt, DMODEL, 3072);
        mgemm_kernel<1, 0, 1><<<dim3(3072 / 128, SEQ / 128), 256, 0, stream>>>(
            (const short*)h, (const short*)Wt, fc_b + l * 3072, nullptr, nullptr, fcb, 3072, DMODEL);
        transp_kernel<<<dim3(DMODEL / 64, 3072 / 64), 256, 0, stream>>>(
            mlp_proj_w + (size_t)l * 3072 * DMODEL, Wt, 3072, DMODEL);
        mgemm_kernel<0, 1, 0><<<dim3(DMODEL / 128, SEQ / 128), 256, 0, stream>>>(
            (const short*)fcb, (const short*)Wt, mlp_proj_b + l * DMODEL, x, x, nullptr, DMODEL, 3072);
    }

    ln_kernel<<<SEQ, 256, 0, stream>>>(x, lnf_w, lnf_b, h);
    transp_kernel<<<dim3(NVPAD / 64, DMODEL / 64), 256, 0, stream>>>(head_w, Wt, DMODEL, NV);
    mgemm_kernel<0, 0, 0><<<dim3(NVPAD / 128, SEQ / 128), 256, 0, stream>>>(
        (const short*)h, (const short*)Wt, head_b, nullptr, logits, nullptr, NV, DMODEL);
    lse_kernel<<<SEQ, 256, 0, stream>>>(logits, lse);
    loss_kernel<<<1, 256, 0, stream>>>(logits, lse, targets, loss);
}

// Round 3
// 1574.330 us; speedup vs baseline: 9.1326x; 2.0056x over previous
//
#include <hip/hip_runtime.h>
#include <hip/hip_bf16.h>
#include <math.h>

using bf16   = __hip_bfloat16;
using f32x4  = __attribute__((ext_vector_type(4))) float;
using bf16x8 = __attribute__((ext_vector_type(8))) short;

constexpr int SEQ    = 2048;
constexpr int DMODEL = 768;
constexpr int NHEAD  = 12;
constexpr int NV     = 50257;
constexpr int NVPAD  = 50304;
constexpr int NLAYER = 4;

__device__ __forceinline__ void gload_lds16(const void* g, void* s) {
    __builtin_amdgcn_global_load_lds((const __attribute__((address_space(1))) void*)g,
                                     (__attribute__((address_space(3))) void*)s, 16, 0, 0);
}

// ---------------- embedding ----------------
__global__ __launch_bounds__(192) void embed_kernel(const int* __restrict__ idx,
                                                    const float* __restrict__ wte,
                                                    const float* __restrict__ wpe,
                                                    float* __restrict__ x) {
    int t = blockIdx.x;
    int tok = idx[t];
    const float4* a = (const float4*)(wte + (size_t)tok * DMODEL);
    const float4* b = (const float4*)(wpe + (size_t)t * DMODEL);
    float4* o = (float4*)(x + (size_t)t * DMODEL);
    int d = threadIdx.x;
    float4 u = a[d], v = b[d];
    u.x += v.x; u.y += v.y; u.z += v.z; u.w += v.w;
    o[d] = u;
}

// ---------------- layernorm: fp32 in, bf16 out ----------------
__global__ __launch_bounds__(256) void ln_kernel(const float* __restrict__ x,
                                                 const float* __restrict__ w,
                                                 const float* __restrict__ b,
                                                 bf16* __restrict__ out) {
    __shared__ float red[8];
    int row = blockIdx.x, tid = threadIdx.x;
    const float* xr = x + (size_t)row * DMODEL;
    float v[3];
    float s = 0.f, ss = 0.f;
#pragma unroll
    for (int j = 0; j < 3; j++) {
        v[j] = xr[tid + j * 256];
        s += v[j];
        ss += v[j] * v[j];
    }
#pragma unroll
    for (int off = 32; off; off >>= 1) {
        s  += __shfl_down(s,  off, 64);
        ss += __shfl_down(ss, off, 64);
    }
    int wid = tid >> 6, lane = tid & 63;
    if (lane == 0) { red[wid] = s; red[4 + wid] = ss; }
    __syncthreads();
    s  = red[0] + red[1] + red[2] + red[3];
    ss = red[4] + red[5] + red[6] + red[7];
    float mean = s * (1.0f / DMODEL);
    float var  = ss * (1.0f / DMODEL) - mean * mean;
    float rstd = rsqrtf(var + 1e-5f);
#pragma unroll
    for (int j = 0; j < 3; j++) {
        int d = tid + j * 256;
        out[(size_t)row * DMODEL + d] = __float2bfloat16((v[j] - mean) * rstd * w[d] + b[d]);
    }
}

// ---------------- transpose + fp32->bf16: W[K][N] -> Wt[Npad][K] ----------------
__global__ __launch_bounds__(256) void transp_kernel(const float* __restrict__ W,
                                                     bf16* __restrict__ Wt,
                                                     int K, int N) {
    __shared__ float t[64][65];
    int n0 = blockIdx.x << 6, k0 = blockIdx.y << 6;
    int tid = threadIdx.x;
#pragma unroll
    for (int i = 0; i < 16; i++) {
        int id = tid + (i << 8);
        int r = id >> 6, c = id & 63;
        int n = n0 + c;
        t[r][c] = (n < N) ? W[(size_t)(k0 + r) * N + n] : 0.0f;
    }
    __syncthreads();
#pragma unroll
    for (int i = 0; i < 16; i++) {
        int id = tid + (i << 8);
        int nr = id >> 6, kc = id & 63;
        Wt[(size_t)(n0 + nr) * K + k0 + kc] = __float2bfloat16(t[kc][nr]);
    }
}

// ---------------- MFMA GEMM: C[M,N] = epi(A[M,K]bf16 @ Wt[N,K]bf16^T) ----------------
template <int ACT, int RES, int OBF>
__global__ __launch_bounds__(256) void mgemm_kernel(const short* __restrict__ A,
                                                    const short* __restrict__ Wt,
                                                    const float* __restrict__ bias,
                                                    const float* __restrict__ res,
                                                    float* __restrict__ outf,
                                                    bf16* __restrict__ outb,
                                                    int N, int K) {
    __shared__ short As[4096];
    __shared__ short Bs[4096];
    int tid = threadIdx.x, lane = tid & 63, wid = tid >> 6;
    int bm = blockIdx.y << 7, bn = blockIdx.x << 7;
    int wr = (wid >> 1) << 6, wc = (wid & 1) << 6;
    f32x4 acc[4][4] = {};
    int rA = tid >> 2, sA = tid & 3;
    int q = lane >> 4, rr = lane & 15;

    for (int k0 = 0; k0 < K; k0 += 32) {
#pragma unroll
        for (int i = 0; i < 2; i++) {
            int r = rA + (i << 6);
            int gc = k0 + ((sA ^ ((r >> 1) & 3)) << 3);
            char* dstA = (char*)As + (i << 12) + (wid << 10);
            char* dstB = (char*)Bs + (i << 12) + (wid << 10);
            gload_lds16(A  + (size_t)(bm + r) * K + gc, dstA);
            gload_lds16(Wt + (size_t)(bn + r) * K + gc, dstB);
        }
        __syncthreads();
        bf16x8 af[4], bfr[4];
#pragma unroll
        for (int m = 0; m < 4; m++) {
            int rowa = wr + (m << 4) + rr;
            af[m]  = *(const bf16x8*)((const char*)As + rowa * 64 + ((q ^ ((rowa >> 1) & 3)) << 4));
            int rowb = wc + (m << 4) + rr;
            bfr[m] = *(const bf16x8*)((const char*)Bs + rowb * 64 + ((q ^ ((rowb >> 1) & 3)) << 4));
        }
#pragma unroll
        for (int m = 0; m < 4; m++)
#pragma unroll
            for (int n = 0; n < 4; n++)
                acc[m][n] = __builtin_amdgcn_mfma_f32_16x16x32_bf16(af[m], bfr[n], acc[m][n], 0, 0, 0);
        __syncthreads();
    }

    int cl = lane & 15, rg = (lane >> 4) << 2;
#pragma unroll
    for (int n = 0; n < 4; n++) {
        int col = bn + wc + (n << 4) + cl;
        if (col < N) {
            float bcol = bias[col];
#pragma unroll
            for (int m = 0; m < 4; m++) {
#pragma unroll
                for (int i = 0; i < 4; i++) {
                    int row = bm + wr + (m << 4) + rg + i;
                    float v = acc[m][n][i] + bcol;
                    if (RES) v += res[(size_t)row * N + col];
                    if (ACT) v = v / (1.0f + __expf(-1.5957691216057308f * (v + 0.044715f * v * v * v)));
                    if (OBF) outb[(size_t)row * N + col] = __float2bfloat16(v);
                    else     outf[(size_t)row * N + col] = v;
                }
            }
        }
    }
}

// ---------------- MFMA flash attention ----------------
// block = (64-row Q tile, head); 4 waves, wave w owns q rows w*16..w*16+15.
// qkv bf16 [t][2304]: q at h*64, k at 768+h*64, v at 1536+h*64.
// LDS: Ks [64 kv][64 d] rows 128B; Vt [64 d][64 kv] rows 128B; Ps per-wave [16 q][64 kv].
// All swizzled on 16B slots: slot' = slot ^ swz(row), swz(r) = (r&7)^((r>>3)&7).
__global__ __launch_bounds__(256) void attn_kernel(const short* __restrict__ qkv,
                                                   bf16* __restrict__ o) {
    __shared__ short Ks[4096];
    __shared__ short Vt[4096];
    __shared__ short Ps[4096];
    int qt = gridDim.x - 1 - blockIdx.x;   // big tiles first
    int h = blockIdx.y, tid = threadIdx.x;
    int lane = tid & 63, w = tid >> 6;
    int g = lane >> 4, c = lane & 15;
    int q0 = qt << 6;

    // Q A-fragments in registers: lane holds Q[q0 + w*16 + c][g*8 + j (+32)]
    bf16x8 qa[2];
    {
        const short* src = qkv + (size_t)(q0 + w * 16 + c) * 2304 + h * 64 + g * 8;
        qa[0] = *(const bf16x8*)src;
        qa[1] = *(const bf16x8*)(src + 32);
    }
    float m_i[4] = {-1e30f, -1e30f, -1e30f, -1e30f};
    float l_i[4] = {};
    f32x4 oacc[4] = {};

    for (int kt = 0; kt <= qt; kt++) {
        __syncthreads();
        // stage K via global_load_lds (source-swizzled, LDS linear)
#pragma unroll
        for (int i = 0; i < 2; i++) {
            int r = (tid >> 3) + i * 32;
            int gslot = (tid & 7) ^ ((r & 7) ^ ((r >> 3) & 7));
            gload_lds16(qkv + (size_t)(kt * 64 + r) * 2304 + 768 + h * 64 + gslot * 8,
                        (char*)Ks + tid * 16 + i * 4096);
        }
        // stage V transposed (reg -> scattered b16 writes)
#pragma unroll
        for (int ci = 0; ci < 2; ci++) {
            int rv = (tid >> 3) + ci * 32;   // kv local
            bf16x8 vv = *(const bf16x8*)(qkv + (size_t)(kt * 64 + rv) * 2304 + 1536 + h * 64 + (tid & 7) * 8);
            int slot = rv >> 3;
#pragma unroll
            for (int j = 0; j < 8; j++) {
                int row = (tid & 7) * 8 + j;  // d
                int sp = slot ^ ((row & 7) ^ ((row >> 3) & 7));
                Vt[row * 64 + sp * 8 + (rv & 7)] = vv[j];
            }
        }
        __syncthreads();

        // S = Q @ K^T (per wave: 16 q rows x 64 kv)
        f32x4 sacc[4] = {};
#pragma unroll
        for (int n = 0; n < 4; n++) {
#pragma unroll
            for (int ks = 0; ks < 2; ks++) {
                int row = n * 16 + c;
                int sp = (ks * 4 + g) ^ ((row & 7) ^ ((row >> 3) & 7));
                bf16x8 kf = *(const bf16x8*)(Ks + row * 64 + sp * 8);
                sacc[n] = __builtin_amdgcn_mfma_f32_16x16x32_bf16(qa[ks], kf, sacc[n], 0, 0, 0);
            }
        }
        // scale + causal mask (C layout: row q = 4g+i, col kv = 16n+c)
#pragma unroll
        for (int n = 0; n < 4; n++)
#pragma unroll
            for (int i = 0; i < 4; i++) {
                float v = sacc[n][i] * 0.125f;
                if (kt == qt && (n * 16 + c > w * 16 + g * 4 + i)) v = -1e30f;
                sacc[n][i] = v;
            }
        // online softmax per q-row
#pragma unroll
        for (int i = 0; i < 4; i++) {
            float rm = fmaxf(fmaxf(sacc[0][i], sacc[1][i]), fmaxf(sacc[2][i], sacc[3][i]));
            rm = fmaxf(rm, __shfl_xor(rm, 1, 16));
            rm = fmaxf(rm, __shfl_xor(rm, 2, 16));
            rm = fmaxf(rm, __shfl_xor(rm, 4, 16));
            rm = fmaxf(rm, __shfl_xor(rm, 8, 16));
            float mn = fmaxf(m_i[i], rm);
            float sc = __expf(m_i[i] - mn);
            m_i[i] = mn;
            float rs = 0.f;
            int row = g * 4 + i;
            int sw = (row & 7) ^ (row >> 3);
#pragma unroll
            for (int n = 0; n < 4; n++) {
                float p = __expf(sacc[n][i] - mn);
                rs += p;
                int sp = (2 * n + (c >> 3)) ^ sw;
                bf16 pb = __float2bfloat16(p);
                Ps[w * 1024 + row * 64 + sp * 8 + (c & 7)] = *reinterpret_cast<short*>(&pb);
            }
            rs += __shfl_xor(rs, 1, 16);
            rs += __shfl_xor(rs, 2, 16);
            rs += __shfl_xor(rs, 4, 16);
            rs += __shfl_xor(rs, 8, 16);
            l_i[i] = l_i[i] * sc + rs;
#pragma unroll
            for (int n = 0; n < 4; n++) oacc[n][i] *= sc;
        }
        // O += P @ V (A-frag from Ps, B-frag from Vt)
        bf16x8 pa[2];
#pragma unroll
        for (int ks = 0; ks < 2; ks++) {
            int sw = (c & 7) ^ (c >> 3);
            int sp = (ks * 4 + g) ^ sw;
            pa[ks] = *(const bf16x8*)(Ps + w * 1024 + c * 64 + sp * 8);
        }
#pragma unroll
        for (int n = 0; n < 4; n++) {
#pragma unroll
            for (int ks = 0; ks < 2; ks++) {
                int row = n * 16 + c;
                int sp = (ks * 4 + g) ^ ((row & 7) ^ ((row >> 3) & 7));
                bf16x8 vf = *(const bf16x8*)(Vt + row * 64 + sp * 8);
                oacc[n] = __builtin_amdgcn_mfma_f32_16x16x32_bf16(pa[ks], vf, oacc[n], 0, 0, 0);
            }
        }
    }
    // epilogue
#pragma unroll
    for (int i = 0; i < 4; i++) {
        float inv = 1.0f / l_i[i];
#pragma unroll
        for (int n = 0; n < 4; n++)
            o[(size_t)(q0 + w * 16 + g * 4 + i) * DMODEL + h * 64 + n * 16 + c] =
                __float2bfloat16(oacc[n][i] * inv);
    }
}

// ---------------- logsumexp per row over vocab ----------------
__global__ __launch_bounds__(256) void lse_kernel(const float* __restrict__ logits,
                                                  float* __restrict__ lse) {
    __shared__ float redm[4], reds[4];
    int row = blockIdx.x, tid = threadIdx.x;
    const float* lr = logits + (size_t)row * NV;
    float m = -1e30f, sum = 0.f;
    for (int c = tid; c < NV; c += 256) {
        float v = lr[c];
        if (v > m) { sum = sum * __expf(m - v) + 1.0f; m = v; }
        else       { sum += __expf(v - m); }
    }
#pragma unroll
    for (int off = 32; off; off >>= 1) {
        float m2 = __shfl_down(m, off, 64), s2 = __shfl_down(sum, off, 64);
        float M = fmaxf(m, m2);
        sum = sum * __expf(m - M) + s2 * __expf(m2 - M);
        m = M;
    }
    int wid = tid >> 6, lane = tid & 63;
    if (lane == 0) { redm[wid] = m; reds[wid] = sum; }
    __syncthreads();
    if (tid == 0) {
        float M = fmaxf(fmaxf(redm[0], redm[1]), fmaxf(redm[2], redm[3]));
        float S = reds[0] * __expf(redm[0] - M) + reds[1] * __expf(redm[1] - M) +
                  reds[2] * __expf(redm[2] - M) + reds[3] * __expf(redm[3] - M);
        lse[row] = M + logf(S);
    }
}

__global__ __launch_bounds__(256) void loss_kernel(const float* __restrict__ logits,
                                                   const float* __restrict__ lse,
                                                   const int* __restrict__ targets,
                                                   float* __restrict__ out) {
    __shared__ float red[4];
    int tid = threadIdx.x;
    float acc = 0.f;
    for (int t = tid; t < SEQ; t += 256)
        acc += lse[t] - logits[(size_t)t * NV + targets[t]];
#pragma unroll
    for (int off = 32; off; off >>= 1) acc += __shfl_down(acc, off, 64);
    int wid = tid >> 6, lane = tid & 63;
    if (lane == 0) red[wid] = acc;
    __syncthreads();
    if (tid == 0) out[0] = (red[0] + red[1] + red[2] + red[3]) * (1.0f / SEQ);
}

extern "C" void kernel_launch(void* const* d_in, const int* in_sizes, int n_in,
                              void* d_out, int out_size, void* d_ws, size_t ws_size,
                              hipStream_t stream) {
    const int*   idx         = (const int*)d_in[0];
    const int*   targets     = (const int*)d_in[1];
    const float* wte         = (const float*)d_in[2];
    const float* wpe         = (const float*)d_in[3];
    const float* ln1_w       = (const float*)d_in[4];
    const float* ln1_b       = (const float*)d_in[5];
    const float* attn_w      = (const float*)d_in[6];
    const float* attn_b      = (const float*)d_in[7];
    const float* attn_proj_w = (const float*)d_in[8];
    const float* attn_proj_b = (const float*)d_in[9];
    const float* ln2_w       = (const float*)d_in[10];
    const float* ln2_b       = (const float*)d_in[11];
    const float* fc_w        = (const float*)d_in[12];
    const float* fc_b        = (const float*)d_in[13];
    const float* mlp_proj_w  = (const float*)d_in[14];
    const float* mlp_proj_b  = (const float*)d_in[15];
    const float* lnf_w       = (const float*)d_in[16];
    const float* lnf_b       = (const float*)d_in[17];
    const float* head_w      = (const float*)d_in[18];
    const float* head_b      = (const float*)d_in[19];

    float* logits = (float*)d_out;
    float* loss   = logits + (size_t)SEQ * NV;

    char* p = (char*)d_ws;
    float* x    = (float*)p;  p += (size_t)SEQ * DMODEL * 4;
    bf16*  h    = (bf16*)p;   p += (size_t)SEQ * DMODEL * 2;
    bf16*  o    = (bf16*)p;   p += (size_t)SEQ * DMODEL * 2;
    bf16*  qkvb = (bf16*)p;   p += (size_t)SEQ * 2304 * 4;
    bf16*  fcb  = (bf16*)p;   p += (size_t)SEQ * 3072 * 2;
    float* lse  = (float*)p;  p += (size_t)SEQ * 4;
    bf16*  Wt   = (bf16*)p;   // up to NVPAD*768 bf16, reused per GEMM

    embed_kernel<<<SEQ, 192, 0, stream>>>(idx, wte, wpe, x);

    for (int l = 0; l < NLAYER; l++) {
        ln_kernel<<<SEQ, 256, 0, stream>>>(x, ln1_w + l * DMODEL, ln1_b + l * DMODEL, h);
        transp_kernel<<<dim3(2304 / 64, DMODEL / 64), 256, 0, stream>>>(
            attn_w + (size_t)l * DMODEL * 2304, Wt, DMODEL, 2304);
        mgemm_kernel<0, 0, 1><<<dim3(2304 / 128, SEQ / 128), 256, 0, stream>>>(
            (const short*)h, (const short*)Wt, attn_b + l * 2304, nullptr, nullptr, qkvb, 2304, DMODEL);
        attn_kernel<<<dim3(SEQ / 64, NHEAD), 256, 0, stream>>>((const short*)qkvb, o);
        transp_kernel<<<dim3(DMODEL / 64, DMODEL / 64), 256, 0, stream>>>(
            attn_proj_w + (size_t)l * DMODEL * DMODEL, Wt, DMODEL, DMODEL);
        mgemm_kernel<0, 1, 0><<<dim3(DMODEL / 128, SEQ / 128), 256, 0, stream>>>(
            (const short*)o, (const short*)Wt, attn_proj_b + l * DMODEL, x, x, nullptr, DMODEL, DMODEL);
        ln_kernel<<<SEQ, 256, 0, stream>>>(x, ln2_w + l * DMODEL, ln2_b + l * DMODEL, h);
        transp_kernel<<<dim3(3072 / 64, DMODEL / 64), 256, 0, stream>>>(
            fc_w + (size_t)l * DMODEL * 3072, Wt, DMODEL, 3072);
        mgemm_kernel<1, 0, 1><<<dim3(3072 / 128, SEQ / 128), 256, 0, stream>>>(
            (const short*)h, (const short*)Wt, fc_b + l * 3072, nullptr, nullptr, fcb, 3072, DMODEL);
        transp_kernel<<<dim3(DMODEL / 64, 3072 / 64), 256, 0, stream>>>(
            mlp_proj_w + (size_t)l * 3072 * DMODEL, Wt, 3072, DMODEL);
        mgemm_kernel<0, 1, 0><<<dim3(DMODEL / 128, SEQ / 128), 256, 0, stream>>>(
            (const short*)fcb, (const short*)Wt, mlp_proj_b + l * DMODEL, x, x, nullptr, DMODEL, 3072);
    }

    ln_kernel<<<SEQ, 256, 0, stream>>>(x, lnf_w, lnf_b, h);
    transp_kernel<<<dim3(NVPAD / 64, DMODEL / 64), 256, 0, stream>>>(head_w, Wt, DMODEL, NV);
    mgemm_kernel<0, 0, 0><<<dim3(NVPAD / 128, SEQ / 128), 256, 0, stream>>>(
        (const short*)h, (const short*)Wt, head_b, nullptr, logits, nullptr, NV, DMODEL);
    lse_kernel<<<SEQ, 256, 0, stream>>>(logits, lse);
    loss_kernel<<<1, 256, 0, stream>>>(logits, lse, targets, loss);
}

// Round 4
// 1485.099 us; speedup vs baseline: 9.6814x; 1.0601x over previous
//
#include <hip/hip_runtime.h>
#include <hip/hip_bf16.h>
#include <math.h>

using bf16   = __hip_bfloat16;
using f32x4  = __attribute__((ext_vector_type(4))) float;
using bf16x8 = __attribute__((ext_vector_type(8))) short;

constexpr int SEQ    = 2048;
constexpr int DMODEL = 768;
constexpr int NHEAD  = 12;
constexpr int NV     = 50257;
constexpr int NVPAD  = 50304;
constexpr int NB     = NVPAD / 128;   // 393 column panels
constexpr int NLAYER = 4;

__device__ __forceinline__ void gload_lds16(const void* g, void* s) {
    __builtin_amdgcn_global_load_lds((const __attribute__((address_space(1))) void*)g,
                                     (__attribute__((address_space(3))) void*)s, 16, 0, 0);
}

// ---------------- embedding ----------------
__global__ __launch_bounds__(192) void embed_kernel(const int* __restrict__ idx,
                                                    const float* __restrict__ wte,
                                                    const float* __restrict__ wpe,
                                                    float* __restrict__ x) {
    int t = blockIdx.x;
    int tok = idx[t];
    const float4* a = (const float4*)(wte + (size_t)tok * DMODEL);
    const float4* b = (const float4*)(wpe + (size_t)t * DMODEL);
    float4* o = (float4*)(x + (size_t)t * DMODEL);
    int d = threadIdx.x;
    float4 u = a[d], v = b[d];
    u.x += v.x; u.y += v.y; u.z += v.z; u.w += v.w;
    o[d] = u;
}

// ---------------- layernorm: fp32 in, bf16 out ----------------
__global__ __launch_bounds__(256) void ln_kernel(const float* __restrict__ x,
                                                 const float* __restrict__ w,
                                                 const float* __restrict__ b,
                                                 bf16* __restrict__ out) {
    __shared__ float red[8];
    int row = blockIdx.x, tid = threadIdx.x;
    const float* xr = x + (size_t)row * DMODEL;
    float v[3];
    float s = 0.f, ss = 0.f;
#pragma unroll
    for (int j = 0; j < 3; j++) {
        v[j] = xr[tid + j * 256];
        s += v[j];
        ss += v[j] * v[j];
    }
#pragma unroll
    for (int off = 32; off; off >>= 1) {
        s  += __shfl_down(s,  off, 64);
        ss += __shfl_down(ss, off, 64);
    }
    int wid = tid >> 6, lane = tid & 63;
    if (lane == 0) { red[wid] = s; red[4 + wid] = ss; }
    __syncthreads();
    s  = red[0] + red[1] + red[2] + red[3];
    ss = red[4] + red[5] + red[6] + red[7];
    float mean = s * (1.0f / DMODEL);
    float var  = ss * (1.0f / DMODEL) - mean * mean;
    float rstd = rsqrtf(var + 1e-5f);
#pragma unroll
    for (int j = 0; j < 3; j++) {
        int d = tid + j * 256;
        out[(size_t)row * DMODEL + d] = __float2bfloat16((v[j] - mean) * rstd * w[d] + b[d]);
    }
}

// ---------------- batched transpose + fp32->bf16: W[K][N] -> Wt[Npad][K] ----------------
__global__ __launch_bounds__(256) void transpb_kernel(const float* __restrict__ W,
                                                      bf16* __restrict__ Wt,
                                                      int K, int N,
                                                      size_t wstride, size_t tstride) {
    __shared__ float t[64][65];
    int l = blockIdx.z;
    W  += (size_t)l * wstride;
    Wt += (size_t)l * tstride;
    int n0 = blockIdx.x << 6, k0 = blockIdx.y << 6;
    int tid = threadIdx.x;
#pragma unroll
    for (int i = 0; i < 16; i++) {
        int id = tid + (i << 8);
        int r = id >> 6, c = id & 63;
        int n = n0 + c;
        t[r][c] = (n < N) ? W[(size_t)(k0 + r) * N + n] : 0.0f;
    }
    __syncthreads();
#pragma unroll
    for (int i = 0; i < 16; i++) {
        int id = tid + (i << 8);
        int nr = id >> 6, kc = id & 63;
        Wt[(size_t)(n0 + nr) * K + k0 + kc] = __float2bfloat16(t[kc][nr]);
    }
}

// ---------------- MFMA GEMM: C[M,N] = epi(A[M,K]bf16 @ Wt[N,K]bf16^T) ----------------
template <int ACT, int RES, int OBF>
__global__ __launch_bounds__(256) void mgemm_kernel(const short* __restrict__ A,
                                                    const short* __restrict__ Wt,
                                                    const float* __restrict__ bias,
                                                    const float* __restrict__ res,
                                                    float* __restrict__ outf,
                                                    bf16* __restrict__ outb,
                                                    int N, int K) {
    __shared__ short As[4096];
    __shared__ short Bs[4096];
    int tid = threadIdx.x, lane = tid & 63, wid = tid >> 6;
    int bm = blockIdx.y << 7, bn = blockIdx.x << 7;
    int wr = (wid >> 1) << 6, wc = (wid & 1) << 6;
    f32x4 acc[4][4] = {};
    int rA = tid >> 2, sA = tid & 3;
    int q = lane >> 4, rr = lane & 15;

    for (int k0 = 0; k0 < K; k0 += 32) {
#pragma unroll
        for (int i = 0; i < 2; i++) {
            int r = rA + (i << 6);
            int gc = k0 + ((sA ^ ((r >> 1) & 3)) << 3);
            char* dstA = (char*)As + (i << 12) + (wid << 10);
            char* dstB = (char*)Bs + (i << 12) + (wid << 10);
            gload_lds16(A  + (size_t)(bm + r) * K + gc, dstA);
            gload_lds16(Wt + (size_t)(bn + r) * K + gc, dstB);
        }
        __syncthreads();
        bf16x8 af[4], bfr[4];
#pragma unroll
        for (int m = 0; m < 4; m++) {
            int rowa = wr + (m << 4) + rr;
            af[m]  = *(const bf16x8*)((const char*)As + rowa * 64 + ((q ^ ((rowa >> 1) & 3)) << 4));
            int rowb = wc + (m << 4) + rr;
            bfr[m] = *(const bf16x8*)((const char*)Bs + rowb * 64 + ((q ^ ((rowb >> 1) & 3)) << 4));
        }
#pragma unroll
        for (int m = 0; m < 4; m++)
#pragma unroll
            for (int n = 0; n < 4; n++)
                acc[m][n] = __builtin_amdgcn_mfma_f32_16x16x32_bf16(af[m], bfr[n], acc[m][n], 0, 0, 0);
        __syncthreads();
    }

    int cl = lane & 15, rg = (lane >> 4) << 2;
#pragma unroll
    for (int n = 0; n < 4; n++) {
        int col = bn + wc + (n << 4) + cl;
        if (col < N) {
            float bcol = bias[col];
#pragma unroll
            for (int m = 0; m < 4; m++) {
#pragma unroll
                for (int i = 0; i < 4; i++) {
                    int row = bm + wr + (m << 4) + rg + i;
                    float v = acc[m][n][i] + bcol;
                    if (RES) v += res[(size_t)row * N + col];
                    if (ACT) v = v / (1.0f + __expf(-1.5957691216057308f * (v + 0.044715f * v * v * v)));
                    if (OBF) outb[(size_t)row * N + col] = __float2bfloat16(v);
                    else     outf[(size_t)row * N + col] = v;
                }
            }
        }
    }
}

// ---------------- head GEMM: logits = A @ Wt^T + b, fused partial-LSE ----------------
// 1D grid 6288 blocks, bijective XCD chunking, M-block fast within chunk.
__global__ __launch_bounds__(256) void head_kernel(const short* __restrict__ A,
                                                   const short* __restrict__ Wt,
                                                   const float* __restrict__ bias,
                                                   float* __restrict__ out,
                                                   float* __restrict__ pm,
                                                   float* __restrict__ ps) {
    __shared__ short As[4096];
    __shared__ short Bs[4096];
    __shared__ float lm[128][2];
    __shared__ float lsum[128][2];
    constexpr int K = DMODEL;
    int bid = blockIdx.x;
    int swz = (bid & 7) * (6288 / 8) + (bid >> 3);
    int bm = (swz & 15) << 7;
    int bxp = swz >> 4;
    int bn = bxp << 7;
    int tid = threadIdx.x, lane = tid & 63, wid = tid >> 6;
    int wr = (wid >> 1) << 6, wc = (wid & 1) << 6;
    f32x4 acc[4][4] = {};
    int rA = tid >> 2, sA = tid & 3;
    int q = lane >> 4, rr = lane & 15;

    for (int k0 = 0; k0 < K; k0 += 32) {
#pragma unroll
        for (int i = 0; i < 2; i++) {
            int r = rA + (i << 6);
            int gc = k0 + ((sA ^ ((r >> 1) & 3)) << 3);
            char* dstA = (char*)As + (i << 12) + (wid << 10);
            char* dstB = (char*)Bs + (i << 12) + (wid << 10);
            gload_lds16(A  + (size_t)(bm + r) * K + gc, dstA);
            gload_lds16(Wt + (size_t)(bn + r) * K + gc, dstB);
        }
        __syncthreads();
        bf16x8 af[4], bfr[4];
#pragma unroll
        for (int m = 0; m < 4; m++) {
            int rowa = wr + (m << 4) + rr;
            af[m]  = *(const bf16x8*)((const char*)As + rowa * 64 + ((q ^ ((rowa >> 1) & 3)) << 4));
            int rowb = wc + (m << 4) + rr;
            bfr[m] = *(const bf16x8*)((const char*)Bs + rowb * 64 + ((q ^ ((rowb >> 1) & 3)) << 4));
        }
#pragma unroll
        for (int m = 0; m < 4; m++)
#pragma unroll
            for (int n = 0; n < 4; n++)
                acc[m][n] = __builtin_amdgcn_mfma_f32_16x16x32_bf16(af[m], bfr[n], acc[m][n], 0, 0, 0);
        __syncthreads();
    }

    int cl = lane & 15, g = lane >> 4;
    // bias + store logits; keep values (or -inf for padded cols) in acc for LSE
#pragma unroll
    for (int n = 0; n < 4; n++) {
        int col = bn + wc + (n << 4) + cl;
        bool valid = col < NV;
        float bcol = valid ? bias[col] : 0.0f;
#pragma unroll
        for (int m = 0; m < 4; m++) {
#pragma unroll
            for (int i = 0; i < 4; i++) {
                int row = bm + wr + (m << 4) + (g << 2) + i;
                float v = acc[m][n][i] + bcol;
                if (valid) out[(size_t)row * NV + col] = v;
                acc[m][n][i] = valid ? v : -1e30f;
            }
        }
    }
    // per-row max over this block's 128 cols
#pragma unroll
    for (int m = 0; m < 4; m++)
#pragma unroll
        for (int i = 0; i < 4; i++) {
            float t = fmaxf(fmaxf(acc[m][0][i], acc[m][1][i]), fmaxf(acc[m][2][i], acc[m][3][i]));
            t = fmaxf(t, __shfl_xor(t, 1, 16));
            t = fmaxf(t, __shfl_xor(t, 2, 16));
            t = fmaxf(t, __shfl_xor(t, 4, 16));
            t = fmaxf(t, __shfl_xor(t, 8, 16));
            if (cl == 0) lm[wr + (m << 4) + (g << 2) + i][wid & 1] = t;
        }
    __syncthreads();
#pragma unroll
    for (int m = 0; m < 4; m++)
#pragma unroll
        for (int i = 0; i < 4; i++) {
            int r = wr + (m << 4) + (g << 2) + i;
            float M = fmaxf(lm[r][0], lm[r][1]);
            float s = 0.f;
#pragma unroll
            for (int n = 0; n < 4; n++) s += __expf(acc[m][n][i] - M);
            s += __shfl_xor(s, 1, 16);
            s += __shfl_xor(s, 2, 16);
            s += __shfl_xor(s, 4, 16);
            s += __shfl_xor(s, 8, 16);
            if (cl == 0) lsum[r][wid & 1] = s;
        }
    __syncthreads();
    if (tid < 128) {
        int r = tid;
        pm[(size_t)(bm + r) * NB + bxp] = fmaxf(lm[r][0], lm[r][1]);
        ps[(size_t)(bm + r) * NB + bxp] = lsum[r][0] + lsum[r][1];
    }
}

// ---------------- LSE reduce over panels: one wave per row ----------------
__global__ __launch_bounds__(256) void lsered_kernel(const float* __restrict__ pm,
                                                     const float* __restrict__ ps,
                                                     float* __restrict__ lse) {
    int row = (blockIdx.x << 2) + (threadIdx.x >> 6);
    int lane = threadIdx.x & 63;
    const float* pmr = pm + (size_t)row * NB;
    const float* psr = ps + (size_t)row * NB;
    float m = -1e30f, s = 0.f;
    for (int j = lane; j < NB; j += 64) {
        float mb = pmr[j], sb = psr[j];
        float M = fmaxf(m, mb);
        s = s * __expf(m - M) + sb * __expf(mb - M);
        m = M;
    }
#pragma unroll
    for (int off = 32; off; off >>= 1) {
        float m2 = __shfl_xor(m, off, 64), s2 = __shfl_xor(s, off, 64);
        float M = fmaxf(m, m2);
        s = s * __expf(m - M) + s2 * __expf(m2 - M);
        m = M;
    }
    if (lane == 0) lse[row] = m + logf(s);
}

// ---------------- MFMA flash attention ----------------
__global__ __launch_bounds__(256) void attn_kernel(const short* __restrict__ qkv,
                                                   bf16* __restrict__ o) {
    __shared__ short Ks[4096];
    __shared__ short Vt[4096];
    __shared__ short Ps[4096];
    int qt = gridDim.x - 1 - blockIdx.x;
    int h = blockIdx.y, tid = threadIdx.x;
    int lane = tid & 63, w = tid >> 6;
    int g = lane >> 4, c = lane & 15;
    int q0 = qt << 6;

    bf16x8 qa[2];
    {
        const short* src = qkv + (size_t)(q0 + w * 16 + c) * 2304 + h * 64 + g * 8;
        qa[0] = *(const bf16x8*)src;
        qa[1] = *(const bf16x8*)(src + 32);
    }
    float m_i[4] = {-1e30f, -1e30f, -1e30f, -1e30f};
    float l_i[4] = {};
    f32x4 oacc[4] = {};

    for (int kt = 0; kt <= qt; kt++) {
        __syncthreads();
#pragma unroll
        for (int i = 0; i < 2; i++) {
            int r = (tid >> 3) + i * 32;
            int gslot = (tid & 7) ^ ((r & 7) ^ ((r >> 3) & 7));
            gload_lds16(qkv + (size_t)(kt * 64 + r) * 2304 + 768 + h * 64 + gslot * 8,
                        (char*)Ks + tid * 16 + i * 4096);
        }
#pragma unroll
        for (int ci = 0; ci < 2; ci++) {
            int rv = (tid >> 3) + ci * 32;
            bf16x8 vv = *(const bf16x8*)(qkv + (size_t)(kt * 64 + rv) * 2304 + 1536 + h * 64 + (tid & 7) * 8);
            int slot = rv >> 3;
#pragma unroll
            for (int j = 0; j < 8; j++) {
                int row = (tid & 7) * 8 + j;
                int sp = slot ^ ((row & 7) ^ ((row >> 3) & 7));
                Vt[row * 64 + sp * 8 + (rv & 7)] = vv[j];
            }
        }
        __syncthreads();

        f32x4 sacc[4] = {};
#pragma unroll
        for (int n = 0; n < 4; n++) {
#pragma unroll
            for (int ks = 0; ks < 2; ks++) {
                int row = n * 16 + c;
                int sp = (ks * 4 + g) ^ ((row & 7) ^ ((row >> 3) & 7));
                bf16x8 kf = *(const bf16x8*)(Ks + row * 64 + sp * 8);
                sacc[n] = __builtin_amdgcn_mfma_f32_16x16x32_bf16(qa[ks], kf, sacc[n], 0, 0, 0);
            }
        }
#pragma unroll
        for (int n = 0; n < 4; n++)
#pragma unroll
            for (int i = 0; i < 4; i++) {
                float v = sacc[n][i] * 0.125f;
                if (kt == qt && (n * 16 + c > w * 16 + g * 4 + i)) v = -1e30f;
                sacc[n][i] = v;
            }
#pragma unroll
        for (int i = 0; i < 4; i++) {
            float rm = fmaxf(fmaxf(sacc[0][i], sacc[1][i]), fmaxf(sacc[2][i], sacc[3][i]));
            rm = fmaxf(rm, __shfl_xor(rm, 1, 16));
            rm = fmaxf(rm, __shfl_xor(rm, 2, 16));
            rm = fmaxf(rm, __shfl_xor(rm, 4, 16));
            rm = fmaxf(rm, __shfl_xor(rm, 8, 16));
            float mn = fmaxf(m_i[i], rm);
            float sc = __expf(m_i[i] - mn);
            m_i[i] = mn;
            float rs = 0.f;
            int row = g * 4 + i;
            int sw = (row & 7) ^ (row >> 3);
#pragma unroll
            for (int n = 0; n < 4; n++) {
                float p = __expf(sacc[n][i] - mn);
                rs += p;
                int sp = (2 * n + (c >> 3)) ^ sw;
                bf16 pb = __float2bfloat16(p);
                Ps[w * 1024 + row * 64 + sp * 8 + (c & 7)] = *reinterpret_cast<short*>(&pb);
            }
            rs += __shfl_xor(rs, 1, 16);
            rs += __shfl_xor(rs, 2, 16);
            rs += __shfl_xor(rs, 4, 16);
            rs += __shfl_xor(rs, 8, 16);
            l_i[i] = l_i[i] * sc + rs;
#pragma unroll
            for (int n = 0; n < 4; n++) oacc[n][i] *= sc;
        }
        bf16x8 pa[2];
#pragma unroll
        for (int ks = 0; ks < 2; ks++) {
            int sw = (c & 7) ^ (c >> 3);
            int sp = (ks * 4 + g) ^ sw;
            pa[ks] = *(const bf16x8*)(Ps + w * 1024 + c * 64 + sp * 8);
        }
#pragma unroll
        for (int n = 0; n < 4; n++) {
#pragma unroll
            for (int ks = 0; ks < 2; ks++) {
                int row = n * 16 + c;
                int sp = (ks * 4 + g) ^ ((row & 7) ^ ((row >> 3) & 7));
                bf16x8 vf = *(const bf16x8*)(Vt + row * 64 + sp * 8);
                oacc[n] = __builtin_amdgcn_mfma_f32_16x16x32_bf16(pa[ks], vf, oacc[n], 0, 0, 0);
            }
        }
    }
#pragma unroll
    for (int i = 0; i < 4; i++) {
        float inv = 1.0f / l_i[i];
#pragma unroll
        for (int n = 0; n < 4; n++)
            o[(size_t)(q0 + w * 16 + g * 4 + i) * DMODEL + h * 64 + n * 16 + c] =
                __float2bfloat16(oacc[n][i] * inv);
    }
}

__global__ __launch_bounds__(256) void loss_kernel(const float* __restrict__ logits,
                                                   const float* __restrict__ lse,
                                                   const int* __restrict__ targets,
                                                   float* __restrict__ out) {
    __shared__ float red[4];
    int tid = threadIdx.x;
    float acc = 0.f;
    for (int t = tid; t < SEQ; t += 256)
        acc += lse[t] - logits[(size_t)t * NV + targets[t]];
#pragma unroll
    for (int off = 32; off; off >>= 1) acc += __shfl_down(acc, off, 64);
    int wid = tid >> 6, lane = tid & 63;
    if (lane == 0) red[wid] = acc;
    __syncthreads();
    if (tid == 0) out[0] = (red[0] + red[1] + red[2] + red[3]) * (1.0f / SEQ);
}

extern "C" void kernel_launch(void* const* d_in, const int* in_sizes, int n_in,
                              void* d_out, int out_size, void* d_ws, size_t ws_size,
                              hipStream_t stream) {
    const int*   idx         = (const int*)d_in[0];
    const int*   targets     = (const int*)d_in[1];
    const float* wte         = (const float*)d_in[2];
    const float* wpe         = (const float*)d_in[3];
    const float* ln1_w       = (const float*)d_in[4];
    const float* ln1_b       = (const float*)d_in[5];
    const float* attn_w      = (const float*)d_in[6];
    const float* attn_b      = (const float*)d_in[7];
    const float* attn_proj_w = (const float*)d_in[8];
    const float* attn_proj_b = (const float*)d_in[9];
    const float* ln2_w       = (const float*)d_in[10];
    const float* ln2_b       = (const float*)d_in[11];
    const float* fc_w        = (const float*)d_in[12];
    const float* fc_b        = (const float*)d_in[13];
    const float* mlp_proj_w  = (const float*)d_in[14];
    const float* mlp_proj_b  = (const float*)d_in[15];
    const float* lnf_w       = (const float*)d_in[16];
    const float* lnf_b       = (const float*)d_in[17];
    const float* head_w      = (const float*)d_in[18];
    const float* head_b      = (const float*)d_in[19];

    float* logits = (float*)d_out;
    float* loss   = logits + (size_t)SEQ * NV;

    char* p = (char*)d_ws;
    float* x    = (float*)p;  p += (size_t)SEQ * DMODEL * 4;
    bf16*  h    = (bf16*)p;   p += (size_t)SEQ * DMODEL * 2;
    bf16*  o    = (bf16*)p;   p += (size_t)SEQ * DMODEL * 2;
    bf16*  qkvb = (bf16*)p;   p += (size_t)SEQ * 2304 * 2;
    bf16*  fcb  = (bf16*)p;   p += (size_t)SEQ * 3072 * 2;
    float* lse  = (float*)p;  p += (size_t)SEQ * 4;
    float* pm   = (float*)p;  p += (size_t)SEQ * NB * 4;
    float* ps   = (float*)p;  p += (size_t)SEQ * NB * 4;
    bf16*  Wt   = (bf16*)p;   // 77.3 MB max (head); layer Wts live in the same region

    bf16* wtA = Wt;                                   // [4][2304*768]
    bf16* wtP = wtA + (size_t)4 * 2304 * 768;         // [4][768*768]
    bf16* wtF = wtP + (size_t)4 * 768 * 768;          // [4][3072*768]
    bf16* wtM = wtF + (size_t)4 * 3072 * 768;         // [4][768*3072]

    embed_kernel<<<SEQ, 192, 0, stream>>>(idx, wte, wpe, x);

    // all layer weight transposes, batched (independent of activations)
    transpb_kernel<<<dim3(2304 / 64, DMODEL / 64, 4), 256, 0, stream>>>(
        attn_w, wtA, DMODEL, 2304, (size_t)DMODEL * 2304, (size_t)2304 * DMODEL);
    transpb_kernel<<<dim3(DMODEL / 64, DMODEL / 64, 4), 256, 0, stream>>>(
        attn_proj_w, wtP, DMODEL, DMODEL, (size_t)DMODEL * DMODEL, (size_t)DMODEL * DMODEL);
    transpb_kernel<<<dim3(3072 / 64, DMODEL / 64, 4), 256, 0, stream>>>(
        fc_w, wtF, DMODEL, 3072, (size_t)DMODEL * 3072, (size_t)3072 * DMODEL);
    transpb_kernel<<<dim3(DMODEL / 64, 3072 / 64, 4), 256, 0, stream>>>(
        mlp_proj_w, wtM, 3072, DMODEL, (size_t)3072 * DMODEL, (size_t)DMODEL * 3072);

    for (int l = 0; l < NLAYER; l++) {
        ln_kernel<<<SEQ, 256, 0, stream>>>(x, ln1_w + l * DMODEL, ln1_b + l * DMODEL, h);
        mgemm_kernel<0, 0, 1><<<dim3(2304 / 128, SEQ / 128), 256, 0, stream>>>(
            (const short*)h, (const short*)(wtA + (size_t)l * 2304 * DMODEL),
            attn_b + l * 2304, nullptr, nullptr, qkvb, 2304, DMODEL);
        attn_kernel<<<dim3(SEQ / 64, NHEAD), 256, 0, stream>>>((const short*)qkvb, o);
        mgemm_kernel<0, 1, 0><<<dim3(DMODEL / 128, SEQ / 128), 256, 0, stream>>>(
            (const short*)o, (const short*)(wtP + (size_t)l * DMODEL * DMODEL),
            attn_proj_b + l * DMODEL, x, x, nullptr, DMODEL, DMODEL);
        ln_kernel<<<SEQ, 256, 0, stream>>>(x, ln2_w + l * DMODEL, ln2_b + l * DMODEL, h);
        mgemm_kernel<1, 0, 1><<<dim3(3072 / 128, SEQ / 128), 256, 0, stream>>>(
            (const short*)h, (const short*)(wtF + (size_t)l * 3072 * DMODEL),
            fc_b + l * 3072, nullptr, nullptr, fcb, 3072, DMODEL);
        mgemm_kernel<0, 1, 0><<<dim3(DMODEL / 128, SEQ / 128), 256, 0, stream>>>(
            (const short*)fcb, (const short*)(wtM + (size_t)l * DMODEL * 3072),
            mlp_proj_b + l * DMODEL, x, x, nullptr, DMODEL, 3072);
    }

    ln_kernel<<<SEQ, 256, 0, stream>>>(x, lnf_w, lnf_b, h);
    transpb_kernel<<<dim3(NVPAD / 64, DMODEL / 64, 1), 256, 0, stream>>>(
        head_w, Wt, DMODEL, NV, 0, 0);
    head_kernel<<<dim3(NB * 16), 256, 0, stream>>>(
        (const short*)h, (const short*)Wt, head_b, logits, pm, ps);
    lsered_kernel<<<SEQ / 4, 256, 0, stream>>>(pm, ps, lse);
    loss_kernel<<<1, 256, 0, stream>>>(logits, lse, targets, loss);
}

// Round 5
// 1358.091 us; speedup vs baseline: 10.5867x; 1.0935x over previous
//
#include <hip/hip_runtime.h>
#include <hip/hip_bf16.h>
#include <math.h>

using bf16   = __hip_bfloat16;
using f32x4  = __attribute__((ext_vector_type(4))) float;
using bf16x8 = __attribute__((ext_vector_type(8))) short;
using s16x4  = __attribute__((ext_vector_type(4))) short;

constexpr int SEQ    = 2048;
constexpr int DMODEL = 768;
constexpr int NHEAD  = 12;
constexpr int NV     = 50257;
constexpr int NVPAD  = 50304;
constexpr int NB     = NVPAD / 128;   // 393 column panels
constexpr int NLAYER = 4;

__device__ __forceinline__ void gload_lds16(const void* g, void* s) {
    __builtin_amdgcn_global_load_lds((const __attribute__((address_space(1))) void*)g,
                                     (__attribute__((address_space(3))) void*)s, 16, 0, 0);
}

// ---------------- embedding ----------------
__global__ __launch_bounds__(192) void embed_kernel(const int* __restrict__ idx,
                                                    const float* __restrict__ wte,
                                                    const float* __restrict__ wpe,
                                                    float* __restrict__ x) {
    int t = blockIdx.x;
    int tok = idx[t];
    const float4* a = (const float4*)(wte + (size_t)tok * DMODEL);
    const float4* b = (const float4*)(wpe + (size_t)t * DMODEL);
    float4* o = (float4*)(x + (size_t)t * DMODEL);
    int d = threadIdx.x;
    float4 u = a[d], v = b[d];
    u.x += v.x; u.y += v.y; u.z += v.z; u.w += v.w;
    o[d] = u;
}

// ---------------- layernorm: fp32 in, bf16 out ----------------
__global__ __launch_bounds__(256) void ln_kernel(const float* __restrict__ x,
                                                 const float* __restrict__ w,
                                                 const float* __restrict__ b,
                                                 bf16* __restrict__ out) {
    __shared__ float red[8];
    int row = blockIdx.x, tid = threadIdx.x;
    const float* xr = x + (size_t)row * DMODEL;
    float v[3];
    float s = 0.f, ss = 0.f;
#pragma unroll
    for (int j = 0; j < 3; j++) {
        v[j] = xr[tid + j * 256];
        s += v[j];
        ss += v[j] * v[j];
    }
#pragma unroll
    for (int off = 32; off; off >>= 1) {
        s  += __shfl_down(s,  off, 64);
        ss += __shfl_down(ss, off, 64);
    }
    int wid = tid >> 6, lane = tid & 63;
    if (lane == 0) { red[wid] = s; red[4 + wid] = ss; }
    __syncthreads();
    s  = red[0] + red[1] + red[2] + red[3];
    ss = red[4] + red[5] + red[6] + red[7];
    float mean = s * (1.0f / DMODEL);
    float var  = ss * (1.0f / DMODEL) - mean * mean;
    float rstd = rsqrtf(var + 1e-5f);
#pragma unroll
    for (int j = 0; j < 3; j++) {
        int d = tid + j * 256;
        out[(size_t)row * DMODEL + d] = __float2bfloat16((v[j] - mean) * rstd * w[d] + b[d]);
    }
}

// ---------------- batched transpose + fp32->bf16: W[K][N] -> Wt[Npad][K] ----------------
__global__ __launch_bounds__(256) void transpb_kernel(const float* __restrict__ W,
                                                      bf16* __restrict__ Wt,
                                                      int K, int N,
                                                      size_t wstride, size_t tstride) {
    __shared__ float t[64][65];
    int l = blockIdx.z;
    W  += (size_t)l * wstride;
    Wt += (size_t)l * tstride;
    int n0 = blockIdx.x << 6, k0 = blockIdx.y << 6;
    int tid = threadIdx.x;
#pragma unroll
    for (int i = 0; i < 16; i++) {
        int id = tid + (i << 8);
        int r = id >> 6, c = id & 63;
        int n = n0 + c;
        t[r][c] = (n < N) ? W[(size_t)(k0 + r) * N + n] : 0.0f;
    }
    __syncthreads();
#pragma unroll
    for (int i = 0; i < 16; i++) {
        int id = tid + (i << 8);
        int nr = id >> 6, kc = id & 63;
        Wt[(size_t)(n0 + nr) * K + k0 + kc] = __float2bfloat16(t[kc][nr]);
    }
}

// ---------------- MFMA GEMM: C[M,N] = epi(A[M,K]bf16 @ Wt[N,K]bf16^T) ----------------
// Swapped operands: D rows = Wt rows (cols of C), D cols = A rows. Lane holds
// 4 consecutive C-cols -> float4 / short4 vector epilogue.
template <int ACT, int RES, int OBF>
__global__ __launch_bounds__(256) void mgemm_kernel(const short* __restrict__ A,
                                                    const short* __restrict__ Wt,
                                                    const float* __restrict__ bias,
                                                    const float* __restrict__ res,
                                                    float* __restrict__ outf,
                                                    bf16* __restrict__ outb,
                                                    int N, int K) {
    __shared__ short As[4096];
    __shared__ short Bs[4096];
    int tid = threadIdx.x, lane = tid & 63, wid = tid >> 6;
    int bm = blockIdx.y << 7, bn = blockIdx.x << 7;
    int wr = (wid >> 1) << 6, wc = (wid & 1) << 6;
    f32x4 acc[4][4] = {};
    int rA = tid >> 2, sA = tid & 3;
    int q = lane >> 4, rr = lane & 15;

    for (int k0 = 0; k0 < K; k0 += 32) {
#pragma unroll
        for (int i = 0; i < 2; i++) {
            int r = rA + (i << 6);
            int gc = k0 + ((sA ^ ((r >> 1) & 3)) << 3);
            char* dstA = (char*)As + (i << 12) + (wid << 10);
            char* dstB = (char*)Bs + (i << 12) + (wid << 10);
            gload_lds16(A  + (size_t)(bm + r) * K + gc, dstA);
            gload_lds16(Wt + (size_t)(bn + r) * K + gc, dstB);
        }
        __syncthreads();
        bf16x8 af[4], bfr[4];
#pragma unroll
        for (int m = 0; m < 4; m++) {
            int rowa = wr + (m << 4) + rr;
            af[m]  = *(const bf16x8*)((const char*)As + rowa * 64 + ((q ^ ((rowa >> 1) & 3)) << 4));
            int rowb = wc + (m << 4) + rr;
            bfr[m] = *(const bf16x8*)((const char*)Bs + rowb * 64 + ((q ^ ((rowb >> 1) & 3)) << 4));
        }
#pragma unroll
        for (int m = 0; m < 4; m++)
#pragma unroll
            for (int n = 0; n < 4; n++)
                acc[m][n] = __builtin_amdgcn_mfma_f32_16x16x32_bf16(bfr[n], af[m], acc[m][n], 0, 0, 0);
        __syncthreads();
    }

    int cl = lane & 15, g = lane >> 4;
#pragma unroll
    for (int m = 0; m < 4; m++) {
        int row = bm + wr + (m << 4) + cl;
#pragma unroll
        for (int n = 0; n < 4; n++) {
            int col0 = bn + wc + (n << 4) + (g << 2);
            float4 bv = *(const float4*)&bias[col0];
            f32x4 v = acc[m][n];
            v[0] += bv.x; v[1] += bv.y; v[2] += bv.z; v[3] += bv.w;
            if (RES) {
                float4 rv = *(const float4*)&res[(size_t)row * N + col0];
                v[0] += rv.x; v[1] += rv.y; v[2] += rv.z; v[3] += rv.w;
            }
            if (ACT) {
#pragma unroll
                for (int j = 0; j < 4; j++)
                    v[j] = v[j] / (1.0f + __expf(-1.5957691216057308f * (v[j] + 0.044715f * v[j] * v[j] * v[j])));
            }
            if (OBF) {
                s16x4 pk;
#pragma unroll
                for (int j = 0; j < 4; j++) {
                    bf16 t = __float2bfloat16(v[j]);
                    pk[j] = *reinterpret_cast<short*>(&t);
                }
                *(s16x4*)&outb[(size_t)row * N + col0] = pk;
            } else {
                *(f32x4*)&outf[(size_t)row * N + col0] = v;
            }
        }
    }
}

// ---------------- head GEMM: logits = A @ Wt^T + b, fused partial-LSE ----------------
// Swapped operands: lane holds 4 consecutive vocab cols of one seq row.
__global__ __launch_bounds__(256) void head_kernel(const short* __restrict__ A,
                                                   const short* __restrict__ Wt,
                                                   const float* __restrict__ bias,
                                                   float* __restrict__ out,
                                                   float* __restrict__ pm,
                                                   float* __restrict__ ps) {
    __shared__ short As[4096];
    __shared__ short Bs[4096];
    __shared__ float lm[128][2];
    __shared__ float lsum[128][2];
    constexpr int K = DMODEL;
    int bid = blockIdx.x;
    int swz = (bid & 7) * (6288 / 8) + (bid >> 3);
    int bm = (swz & 15) << 7;      // seq block
    int bxp = swz >> 4;            // vocab panel
    int bn = bxp << 7;
    int tid = threadIdx.x, lane = tid & 63, wid = tid >> 6;
    int wr = (wid >> 1) << 6;      // seq half
    int wc = (wid & 1) << 6;       // vocab half
    f32x4 acc[4][4] = {};
    int rA = tid >> 2, sA = tid & 3;
    int q = lane >> 4, rr = lane & 15;

    for (int k0 = 0; k0 < K; k0 += 32) {
#pragma unroll
        for (int i = 0; i < 2; i++) {
            int r = rA + (i << 6);
            int gc = k0 + ((sA ^ ((r >> 1) & 3)) << 3);
            char* dstA = (char*)As + (i << 12) + (wid << 10);
            char* dstB = (char*)Bs + (i << 12) + (wid << 10);
            gload_lds16(A  + (size_t)(bm + r) * K + gc, dstA);
            gload_lds16(Wt + (size_t)(bn + r) * K + gc, dstB);
        }
        __syncthreads();
        bf16x8 af[4], bfr[4];
#pragma unroll
        for (int m = 0; m < 4; m++) {
            int rowa = wr + (m << 4) + rr;
            af[m]  = *(const bf16x8*)((const char*)As + rowa * 64 + ((q ^ ((rowa >> 1) & 3)) << 4));
            int rowb = wc + (m << 4) + rr;
            bfr[m] = *(const bf16x8*)((const char*)Bs + rowb * 64 + ((q ^ ((rowb >> 1) & 3)) << 4));
        }
#pragma unroll
        for (int m = 0; m < 4; m++)
#pragma unroll
            for (int n = 0; n < 4; n++)
                acc[m][n] = __builtin_amdgcn_mfma_f32_16x16x32_bf16(bfr[n], af[m], acc[m][n], 0, 0, 0);
        __syncthreads();
    }

    int cl = lane & 15, g = lane >> 4;
    // bias + store logits (float4); keep biased values (or -1e30) in acc for LSE
#pragma unroll
    for (int m = 0; m < 4; m++) {
        int row = bm + wr + (m << 4) + cl;
#pragma unroll
        for (int n = 0; n < 4; n++) {
            int col0 = bn + wc + (n << 4) + (g << 2);
            f32x4 v = acc[m][n];
            if (col0 + 3 < NV) {
                float4 bv = *(const float4*)&bias[col0];
                v[0] += bv.x; v[1] += bv.y; v[2] += bv.z; v[3] += bv.w;
                *(f32x4*)&out[(size_t)row * NV + col0] = v;
            } else {
#pragma unroll
                for (int j = 0; j < 4; j++) {
                    if (col0 + j < NV) {
                        v[j] += bias[col0 + j];
                        out[(size_t)row * NV + col0 + j] = v[j];
                    } else {
                        v[j] = -1e30f;
                    }
                }
            }
            acc[m][n] = v;
        }
    }
    // per-row (seq) max over this block's 128 vocab cols
#pragma unroll
    for (int m = 0; m < 4; m++) {
        float t = -1e30f;
#pragma unroll
        for (int n = 0; n < 4; n++)
#pragma unroll
            for (int j = 0; j < 4; j++) t = fmaxf(t, acc[m][n][j]);
        t = fmaxf(t, __shfl_xor(t, 16, 64));
        t = fmaxf(t, __shfl_xor(t, 32, 64));
        if (g == 0) lm[wr + (m << 4) + cl][wid & 1] = t;
    }
    __syncthreads();
#pragma unroll
    for (int m = 0; m < 4; m++) {
        int r = wr + (m << 4) + cl;
        float M = fmaxf(lm[r][0], lm[r][1]);
        float s = 0.f;
#pragma unroll
        for (int n = 0; n < 4; n++)
#pragma unroll
            for (int j = 0; j < 4; j++) s += __expf(acc[m][n][j] - M);
        s += __shfl_xor(s, 16, 64);
        s += __shfl_xor(s, 32, 64);
        if (g == 0) lsum[r][wid & 1] = s;
    }
    __syncthreads();
    if (tid < 128) {
        int r = tid;
        pm[(size_t)(bm + r) * NB + bxp] = fmaxf(lm[r][0], lm[r][1]);
        ps[(size_t)(bm + r) * NB + bxp] = lsum[r][0] + lsum[r][1];
    }
}

// ---------------- LSE reduce over panels: one wave per row ----------------
__global__ __launch_bounds__(256) void lsered_kernel(const float* __restrict__ pm,
                                                     const float* __restrict__ ps,
                                                     float* __restrict__ lse) {
    int row = (blockIdx.x << 2) + (threadIdx.x >> 6);
    int lane = threadIdx.x & 63;
    const float* pmr = pm + (size_t)row * NB;
    const float* psr = ps + (size_t)row * NB;
    float m = -1e30f, s = 0.f;
    for (int j = lane; j < NB; j += 64) {
        float mb = pmr[j], sb = psr[j];
        float M = fmaxf(m, mb);
        s = s * __expf(m - M) + sb * __expf(mb - M);
        m = M;
    }
#pragma unroll
    for (int off = 32; off; off >>= 1) {
        float m2 = __shfl_xor(m, off, 64), s2 = __shfl_xor(s, off, 64);
        float M = fmaxf(m, m2);
        s = s * __expf(m - M) + s2 * __expf(m2 - M);
        m = M;
    }
    if (lane == 0) lse[row] = m + logf(s);
}

// ---------------- MFMA flash attention ----------------
__global__ __launch_bounds__(256) void attn_kernel(const short* __restrict__ qkv,
                                                   bf16* __restrict__ o) {
    __shared__ short Ks[4096];
    __shared__ short Vt[4096];
    __shared__ short Ps[4096];
    int qt = gridDim.x - 1 - blockIdx.x;
    int h = blockIdx.y, tid = threadIdx.x;
    int lane = tid & 63, w = tid >> 6;
    int g = lane >> 4, c = lane & 15;
    int q0 = qt << 6;

    bf16x8 qa[2];
    {
        const short* src = qkv + (size_t)(q0 + w * 16 + c) * 2304 + h * 64 + g * 8;
        qa[0] = *(const bf16x8*)src;
        qa[1] = *(const bf16x8*)(src + 32);
    }
    float m_i[4] = {-1e30f, -1e30f, -1e30f, -1e30f};
    float l_i[4] = {};
    f32x4 oacc[4] = {};

    for (int kt = 0; kt <= qt; kt++) {
        __syncthreads();
#pragma unroll
        for (int i = 0; i < 2; i++) {
            int r = (tid >> 3) + i * 32;
            int gslot = (tid & 7) ^ ((r & 7) ^ ((r >> 3) & 7));
            gload_lds16(qkv + (size_t)(kt * 64 + r) * 2304 + 768 + h * 64 + gslot * 8,
                        (char*)Ks + tid * 16 + i * 4096);
        }
#pragma unroll
        for (int ci = 0; ci < 2; ci++) {
            int rv = (tid >> 3) + ci * 32;
            bf16x8 vv = *(const bf16x8*)(qkv + (size_t)(kt * 64 + rv) * 2304 + 1536 + h * 64 + (tid & 7) * 8);
            int slot = rv >> 3;
#pragma unroll
            for (int j = 0; j < 8; j++) {
                int row = (tid & 7) * 8 + j;
                int sp = slot ^ ((row & 7) ^ ((row >> 3) & 7));
                Vt[row * 64 + sp * 8 + (rv & 7)] = vv[j];
            }
        }
        __syncthreads();

        f32x4 sacc[4] = {};
#pragma unroll
        for (int n = 0; n < 4; n++) {
#pragma unroll
            for (int ks = 0; ks < 2; ks++) {
                int row = n * 16 + c;
                int sp = (ks * 4 + g) ^ ((row & 7) ^ ((row >> 3) & 7));
                bf16x8 kf = *(const bf16x8*)(Ks + row * 64 + sp * 8);
                sacc[n] = __builtin_amdgcn_mfma_f32_16x16x32_bf16(qa[ks], kf, sacc[n], 0, 0, 0);
            }
        }
#pragma unroll
        for (int n = 0; n < 4; n++)
#pragma unroll
            for (int i = 0; i < 4; i++) {
                float v = sacc[n][i] * 0.125f;
                if (kt == qt && (n * 16 + c > w * 16 + g * 4 + i)) v = -1e30f;
                sacc[n][i] = v;
            }
#pragma unroll
        for (int i = 0; i < 4; i++) {
            float rm = fmaxf(fmaxf(sacc[0][i], sacc[1][i]), fmaxf(sacc[2][i], sacc[3][i]));
            rm = fmaxf(rm, __shfl_xor(rm, 1, 16));
            rm = fmaxf(rm, __shfl_xor(rm, 2, 16));
            rm = fmaxf(rm, __shfl_xor(rm, 4, 16));
            rm = fmaxf(rm, __shfl_xor(rm, 8, 16));
            float mn = fmaxf(m_i[i], rm);
            float sc = __expf(m_i[i] - mn);
            m_i[i] = mn;
            float rs = 0.f;
            int row = g * 4 + i;
            int sw = (row & 7) ^ (row >> 3);
#pragma unroll
            for (int n = 0; n < 4; n++) {
                float p = __expf(sacc[n][i] - mn);
                rs += p;
                int sp = (2 * n + (c >> 3)) ^ sw;
                bf16 pb = __float2bfloat16(p);
                Ps[w * 1024 + row * 64 + sp * 8 + (c & 7)] = *reinterpret_cast<short*>(&pb);
            }
            rs += __shfl_xor(rs, 1, 16);
            rs += __shfl_xor(rs, 2, 16);
            rs += __shfl_xor(rs, 4, 16);
            rs += __shfl_xor(rs, 8, 16);
            l_i[i] = l_i[i] * sc + rs;
#pragma unroll
            for (int n = 0; n < 4; n++) oacc[n][i] *= sc;
        }
        bf16x8 pa[2];
#pragma unroll
        for (int ks = 0; ks < 2; ks++) {
            int sw = (c & 7) ^ (c >> 3);
            int sp = (ks * 4 + g) ^ sw;
            pa[ks] = *(const bf16x8*)(Ps + w * 1024 + c * 64 + sp * 8);
        }
#pragma unroll
        for (int n = 0; n < 4; n++) {
#pragma unroll
            for (int ks = 0; ks < 2; ks++) {
                int row = n * 16 + c;
                int sp = (ks * 4 + g) ^ ((row & 7) ^ ((row >> 3) & 7));
                bf16x8 vf = *(const bf16x8*)(Vt + row * 64 + sp * 8);
                oacc[n] = __builtin_amdgcn_mfma_f32_16x16x32_bf16(pa[ks], vf, oacc[n], 0, 0, 0);
            }
        }
    }
#pragma unroll
    for (int i = 0; i < 4; i++) {
        float inv = 1.0f / l_i[i];
#pragma unroll
        for (int n = 0; n < 4; n++)
            o[(size_t)(q0 + w * 16 + g * 4 + i) * DMODEL + h * 64 + n * 16 + c] =
                __float2bfloat16(oacc[n][i] * inv);
    }
}

__global__ __launch_bounds__(256) void loss_kernel(const float* __restrict__ logits,
                                                   const float* __restrict__ lse,
                                                   const int* __restrict__ targets,
                                                   float* __restrict__ out) {
    __shared__ float red[4];
    int tid = threadIdx.x;
    float acc = 0.f;
    for (int t = tid; t < SEQ; t += 256)
        acc += lse[t] - logits[(size_t)t * NV + targets[t]];
#pragma unroll
    for (int off = 32; off; off >>= 1) acc += __shfl_down(acc, off, 64);
    int wid = tid >> 6, lane = tid & 63;
    if (lane == 0) red[wid] = acc;
    __syncthreads();
    if (tid == 0) out[0] = (red[0] + red[1] + red[2] + red[3]) * (1.0f / SEQ);
}

extern "C" void kernel_launch(void* const* d_in, const int* in_sizes, int n_in,
                              void* d_out, int out_size, void* d_ws, size_t ws_size,
                              hipStream_t stream) {
    const int*   idx         = (const int*)d_in[0];
    const int*   targets     = (const int*)d_in[1];
    const float* wte         = (const float*)d_in[2];
    const float* wpe         = (const float*)d_in[3];
    const float* ln1_w       = (const float*)d_in[4];
    const float* ln1_b       = (const float*)d_in[5];
    const float* attn_w      = (const float*)d_in[6];
    const float* attn_b      = (const float*)d_in[7];
    const float* attn_proj_w = (const float*)d_in[8];
    const float* attn_proj_b = (const float*)d_in[9];
    const float* ln2_w       = (const float*)d_in[10];
    const float* ln2_b       = (const float*)d_in[11];
    const float* fc_w        = (const float*)d_in[12];
    const float* fc_b        = (const float*)d_in[13];
    const float* mlp_proj_w  = (const float*)d_in[14];
    const float* mlp_proj_b  = (const float*)d_in[15];
    const float* lnf_w       = (const float*)d_in[16];
    const float* lnf_b       = (const float*)d_in[17];
    const float* head_w      = (const float*)d_in[18];
    const float* head_b      = (const float*)d_in[19];

    float* logits = (float*)d_out;
    float* loss   = logits + (size_t)SEQ * NV;

    char* p = (char*)d_ws;
    float* x    = (float*)p;  p += (size_t)SEQ * DMODEL * 4;
    bf16*  h    = (bf16*)p;   p += (size_t)SEQ * DMODEL * 2;
    bf16*  o    = (bf16*)p;   p += (size_t)SEQ * DMODEL * 2;
    bf16*  qkvb = (bf16*)p;   p += (size_t)SEQ * 2304 * 2;
    bf16*  fcb  = (bf16*)p;   p += (size_t)SEQ * 3072 * 2;
    float* lse  = (float*)p;  p += (size_t)SEQ * 4;
    float* pm   = (float*)p;  p += (size_t)SEQ * NB * 4;
    float* ps   = (float*)p;  p += (size_t)SEQ * NB * 4;
    bf16*  Wt   = (bf16*)p;   // 77.3 MB max (head); layer Wts live in the same region

    bf16* wtA = Wt;                                   // [4][2304*768]
    bf16* wtP = wtA + (size_t)4 * 2304 * 768;         // [4][768*768]
    bf16* wtF = wtP + (size_t)4 * 768 * 768;          // [4][3072*768]
    bf16* wtM = wtF + (size_t)4 * 3072 * 768;         // [4][768*3072]

    embed_kernel<<<SEQ, 192, 0, stream>>>(idx, wte, wpe, x);

    transpb_kernel<<<dim3(2304 / 64, DMODEL / 64, 4), 256, 0, stream>>>(
        attn_w, wtA, DMODEL, 2304, (size_t)DMODEL * 2304, (size_t)2304 * DMODEL);
    transpb_kernel<<<dim3(DMODEL / 64, DMODEL / 64, 4), 256, 0, stream>>>(
        attn_proj_w, wtP, DMODEL, DMODEL, (size_t)DMODEL * DMODEL, (size_t)DMODEL * DMODEL);
    transpb_kernel<<<dim3(3072 / 64, DMODEL / 64, 4), 256, 0, stream>>>(
        fc_w, wtF, DMODEL, 3072, (size_t)DMODEL * 3072, (size_t)3072 * DMODEL);
    transpb_kernel<<<dim3(DMODEL / 64, 3072 / 64, 4), 256, 0, stream>>>(
        mlp_proj_w, wtM, 3072, DMODEL, (size_t)3072 * DMODEL, (size_t)DMODEL * 3072);

    for (int l = 0; l < NLAYER; l++) {
        ln_kernel<<<SEQ, 256, 0, stream>>>(x, ln1_w + l * DMODEL, ln1_b + l * DMODEL, h);
        mgemm_kernel<0, 0, 1><<<dim3(2304 / 128, SEQ / 128), 256, 0, stream>>>(
            (const short*)h, (const short*)(wtA + (size_t)l * 2304 * DMODEL),
            attn_b + l * 2304, nullptr, nullptr, qkvb, 2304, DMODEL);
        attn_kernel<<<dim3(SEQ / 64, NHEAD), 256, 0, stream>>>((const short*)qkvb, o);
        mgemm_kernel<0, 1, 0><<<dim3(DMODEL / 128, SEQ / 128), 256, 0, stream>>>(
            (const short*)o, (const short*)(wtP + (size_t)l * DMODEL * DMODEL),
            attn_proj_b + l * DMODEL, x, x, nullptr, DMODEL, DMODEL);
        ln_kernel<<<SEQ, 256, 0, stream>>>(x, ln2_w + l * DMODEL, ln2_b + l * DMODEL, h);
        mgemm_kernel<1, 0, 1><<<dim3(3072 / 128, SEQ / 128), 256, 0, stream>>>(
            (const short*)h, (const short*)(wtF + (size_t)l * 3072 * DMODEL),
            fc_b + l * 3072, nullptr, nullptr, fcb, 3072, DMODEL);
        mgemm_kernel<0, 1, 0><<<dim3(DMODEL / 128, SEQ / 128), 256, 0, stream>>>(
            (const short*)fcb, (const short*)(wtM + (size_t)l * DMODEL * 3072),
            mlp_proj_b + l * DMODEL, x, x, nullptr, DMODEL, 3072);
    }

    ln_kernel<<<SEQ, 256, 0, stream>>>(x, lnf_w, lnf_b, h);
    transpb_kernel<<<dim3(NVPAD / 64, DMODEL / 64, 1), 256, 0, stream>>>(
        head_w, Wt, DMODEL, NV, 0, 0);
    head_kernel<<<dim3(NB * 16), 256, 0, stream>>>(
        (const short*)h, (const short*)Wt, head_b, logits, pm, ps);
    lsered_kernel<<<SEQ / 4, 256, 0, stream>>>(pm, ps, lse);
    loss_kernel<<<1, 256, 0, stream>>>(logits, lse, targets, loss);
}